// Round 12
// baseline (901.488 us; speedup 1.0000x reference)
//
#include <hip/hip_runtime.h>
#include <hip/hip_bf16.h>
#include <math.h>

#define DV 1024
#define FF 4096
#define NLAY 6
#define NH 16
#define TT 1024
#define NTOK 2048

typedef float f32x4 __attribute__((ext_vector_type(4)));
typedef short bf16x8 __attribute__((ext_vector_type(8)));
typedef unsigned short u16;
typedef u16 u16x4 __attribute__((ext_vector_type(4)));
typedef u16 u16x8 __attribute__((ext_vector_type(8)));

__device__ __forceinline__ u16 f2b(float f) {
  unsigned u = __float_as_uint(f);
  unsigned r = (u + 0x7fffu + ((u >> 16) & 1u)) >> 16;  // RNE, finite inputs
  return (u16)r;
}
__device__ __forceinline__ float b2f(u16 u) {
  return __uint_as_float(((unsigned)u) << 16);
}

__device__ __forceinline__ void gload_lds16(const void* g, void* lds) {
  __builtin_amdgcn_global_load_lds(
      (const __attribute__((address_space(1))) void*)g,
      (__attribute__((address_space(3))) void*)lds, 16, 0, 0);
}

// ---------- embed + LN1(layer0) fused ----------
__global__ __launch_bounds__(256) void embed_ln_k(const int* __restrict__ ids,
                                                  const float* __restrict__ wte,
                                                  const float* __restrict__ wpe,
                                                  const float* __restrict__ gg,
                                                  const float* __restrict__ bb,
                                                  float* __restrict__ X,
                                                  u16* __restrict__ outb) {
  int row = blockIdx.x, tid = threadIdx.x;
  int t = row & (TT - 1);
  int id = ids[row];
  f32x4 a = *(const f32x4*)(wte + (size_t)id * DV + tid * 4);
  f32x4 p = *(const f32x4*)(wpe + (size_t)t * DV + tid * 4);
  f32x4 v = a + p;
  *(f32x4*)(X + (size_t)row * DV + tid * 4) = v;
  float s1 = v[0] + v[1] + v[2] + v[3];
  float s2 = v[0] * v[0] + v[1] * v[1] + v[2] * v[2] + v[3] * v[3];
#pragma unroll
  for (int o = 32; o >= 1; o >>= 1) {
    s1 += __shfl_xor(s1, o);
    s2 += __shfl_xor(s2, o);
  }
  __shared__ float sh[8];
  int w = tid >> 6;
  if ((tid & 63) == 0) { sh[w] = s1; sh[w + 4] = s2; }
  __syncthreads();
  s1 = sh[0] + sh[1] + sh[2] + sh[3];
  s2 = sh[4] + sh[5] + sh[6] + sh[7];
  float mean = s1 * (1.0f / DV);
  float var = s2 * (1.0f / DV) - mean * mean;
  float rstd = rsqrtf(var + 1e-5f);
  f32x4 gv = *(const f32x4*)(gg + tid * 4);
  f32x4 bv = *(const f32x4*)(bb + tid * 4);
  u16x4 r;
#pragma unroll
  for (int i = 0; i < 4; ++i) r[i] = f2b((v[i] - mean) * rstd * gv[i] + bv[i]);
  *(u16x4*)(outb + (size_t)row * DV + tid * 4) = r;
}

// ---------- plain LN (fallback path) ----------
template <int OUTF>
__global__ __launch_bounds__(256) void ln_k(const float* __restrict__ X,
                                            const float* __restrict__ gg,
                                            const float* __restrict__ bb,
                                            u16* __restrict__ outb,
                                            float* __restrict__ outf) {
  int row = blockIdx.x, tid = threadIdx.x;
  f32x4 v = *(const f32x4*)(X + (size_t)row * DV + tid * 4);
  float s1 = v[0] + v[1] + v[2] + v[3];
  float s2 = v[0] * v[0] + v[1] * v[1] + v[2] * v[2] + v[3] * v[3];
#pragma unroll
  for (int o = 32; o >= 1; o >>= 1) {
    s1 += __shfl_xor(s1, o);
    s2 += __shfl_xor(s2, o);
  }
  __shared__ float sh[8];
  int w = tid >> 6;
  if ((tid & 63) == 0) { sh[w] = s1; sh[w + 4] = s2; }
  __syncthreads();
  s1 = sh[0] + sh[1] + sh[2] + sh[3];
  s2 = sh[4] + sh[5] + sh[6] + sh[7];
  float mean = s1 * (1.0f / DV);
  float var = s2 * (1.0f / DV) - mean * mean;
  float rstd = rsqrtf(var + 1e-5f);
  f32x4 gv = *(const f32x4*)(gg + tid * 4);
  f32x4 bv = *(const f32x4*)(bb + tid * 4);
  f32x4 o;
#pragma unroll
  for (int i = 0; i < 4; ++i) o[i] = (v[i] - mean) * rstd * gv[i] + bv[i];
  if (OUTF) {
    *(f32x4*)(outf + (size_t)row * DV + tid * 4) = o;
  } else {
    u16x4 r = {f2b(o[0]), f2b(o[1]), f2b(o[2]), f2b(o[3])};
    *(u16x4*)(outb + (size_t)row * DV + tid * 4) = r;
  }
}

// ---------- fused: x += bias + sum(bf16 partials); LN(x) ----------
template <int NS, int OUTF>
__global__ __launch_bounds__(256) void reduce_ln_k(
    float* __restrict__ X, const u16* __restrict__ pp,
    const float* __restrict__ bias, const float* __restrict__ gg,
    const float* __restrict__ bb, u16* __restrict__ outb,
    float* __restrict__ outf) {
  int row = blockIdx.x, tid = threadIdx.x;
  size_t off = (size_t)row * DV + tid * 4;
  f32x4 v = *(const f32x4*)(X + off);
  if (NS > 0) {
    f32x4 bvv = *(const f32x4*)(bias + tid * 4);
    v += bvv;
#pragma unroll
    for (int s = 0; s < NS; ++s) {
      u16x4 pv = *(const u16x4*)(pp + (size_t)s * NTOK * DV + off);
      v[0] += b2f(pv[0]); v[1] += b2f(pv[1]);
      v[2] += b2f(pv[2]); v[3] += b2f(pv[3]);
    }
    *(f32x4*)(X + off) = v;
  }
  float s1 = v[0] + v[1] + v[2] + v[3];
  float s2 = v[0] * v[0] + v[1] * v[1] + v[2] * v[2] + v[3] * v[3];
#pragma unroll
  for (int o = 32; o >= 1; o >>= 1) {
    s1 += __shfl_xor(s1, o);
    s2 += __shfl_xor(s2, o);
  }
  __shared__ float sh[8];
  int w = tid >> 6;
  if ((tid & 63) == 0) { sh[w] = s1; sh[w + 4] = s2; }
  __syncthreads();
  s1 = sh[0] + sh[1] + sh[2] + sh[3];
  s2 = sh[4] + sh[5] + sh[6] + sh[7];
  float mean = s1 * (1.0f / DV);
  float var = s2 * (1.0f / DV) - mean * mean;
  float rstd = rsqrtf(var + 1e-5f);
  f32x4 gv = *(const f32x4*)(gg + tid * 4);
  f32x4 bv = *(const f32x4*)(bb + tid * 4);
  f32x4 o;
#pragma unroll
  for (int i = 0; i < 4; ++i) o[i] = (v[i] - mean) * rstd * gv[i] + bv[i];
  if (OUTF) {
    *(f32x4*)(outf + off) = o;
  } else {
    u16x4 r = {f2b(o[0]), f2b(o[1]), f2b(o[2]), f2b(o[3])};
    *(u16x4*)(outb + off) = r;
  }
}

// ---------- weight transpose: W[K][N] f32 -> WT[N][K] bf16 (retired from tuning) ----------
__global__ __launch_bounds__(256) void transw_k(const float* __restrict__ wq,
                                                const float* __restrict__ wk,
                                                const float* __restrict__ wv,
                                                const float* __restrict__ wo,
                                                const float* __restrict__ w1,
                                                const float* __restrict__ w2,
                                                u16* __restrict__ WT) {
  int lay = blockIdx.y;
  size_t oDD = (size_t)lay * DV * DV, oDF = (size_t)lay * DV * FF;
  u16* WTL = WT + (size_t)lay * 12 * 1024 * 1024;
  int bid = blockIdx.x;
  const float* src;
  u16* dst;
  int K, N, tile;
  if (bid < 256) {
    int which = bid >> 6;
    src = (which == 0 ? wq : which == 1 ? wk : which == 2 ? wv : wo) + oDD;
    dst = WTL + (size_t)which * (DV * DV);
    K = DV; N = DV; tile = bid & 63;
  } else if (bid < 512) {
    src = w1 + oDF; dst = WTL + (size_t)4 * (DV * DV); K = DV; N = FF; tile = bid - 256;
  } else {
    src = w2 + oDF; dst = WTL + (size_t)8 * (DV * DV); K = FF; N = DV; tile = bid - 512;
  }
  int ntc = N >> 8;
  int tr = tile / ntc, tc = tile - tr * ntc;
  int k0 = tr * 64, n0 = tc * 256;
  __shared__ u16 ts[64][258];
  int tid = threadIdx.x, l = tid & 63, w = tid >> 6;
  f32x4 vv[16];
#pragma unroll
  for (int i = 0; i < 16; ++i)
    vv[i] = *(const f32x4*)(src + (size_t)(k0 + i * 4 + w) * N + n0 + l * 4);
#pragma unroll
  for (int i = 0; i < 16; ++i) {
    u16x4 c = {f2b(vv[i][0]), f2b(vv[i][1]), f2b(vv[i][2]), f2b(vv[i][3])};
    *(u16x4*)(&ts[i * 4 + w][l * 4]) = c;
  }
  __syncthreads();
  int kk = (tid & 7) * 8, nn = tid >> 3;
#pragma unroll
  for (int j = 0; j < 8; ++j) {
    int n = j * 32 + nn;
    u16x8 ov;
#pragma unroll
    for (int m = 0; m < 8; ++m) ov[m] = ts[kk + m][n];
    *(u16x8*)(dst + (size_t)(n0 + n) * K + k0 + kk) = ov;
  }
}

// ---------- GEMM 128x128: 512 thr / 8 waves, BK=64 dbuf, T2 swizzle ----------
// EPI 0: bf16 out + bias; z==0 -> o0 SCALED 0.125 (Q); z==1 -> o1; z==2 -> b2v, TRANSPOSED o2t
// EPI 2: f32 out = res + C + bias (fallback, unstaged)
// EPI 3: bf16 raw partial to op + z*M*N, K range [z*KS,(z+1)*KS)
template <int EPI>
__global__ __launch_bounds__(512) void gemm_k(
    const u16* __restrict__ A, const u16* __restrict__ Wt,
    const float* __restrict__ b0, const float* __restrict__ b1,
    const float* __restrict__ b2v, u16* __restrict__ o0, u16* __restrict__ o1,
    u16* __restrict__ o2t, u16* __restrict__ op, float* __restrict__ of,
    const float* __restrict__ res, int M, int N, int K, int KS) {
  int z = blockIdx.z;
  const u16* W = Wt;
  const float* bias = b0;
  u16* outb = o0;
  if (EPI == 0) {
    W = Wt + (size_t)z * N * K;
    bias = z == 0 ? b0 : z == 1 ? b1 : b2v;
    outb = z == 0 ? o0 : o1;
  }
  int gx = gridDim.x, nwg = gx * gridDim.y;
  int lin = blockIdx.y * gx + blockIdx.x;
  int cpx = nwg >> 3;
  int swz = (lin & 7) * cpx + (lin >> 3);
  int bm = (swz % gx) * 128, bn = (swz / gx) * 128;
  int kbeg = (EPI == 3) ? z * KS : 0;
  int klen = (EPI == 3) ? KS : K;
  __shared__ __attribute__((aligned(16))) u16 SM[32768];  // 64 KB
  u16* As = SM;
  u16* Bs = SM + 16384;
  u16* Cs = SM;
  int tid = threadIdx.x, l = tid & 63, w = tid >> 6;
  int q = l & 15, g = l >> 4;
  int wm = (w >> 1) * 32, wn = (w & 1) * 64;
  int srow = w * 16 + (l >> 3);
  int scol = (((l & 7) ^ ((l >> 3) & 7))) * 8;
  const u16* Ab = A + (size_t)(bm + srow) * K + kbeg + scol;
  const u16* Wb = W + (size_t)(bn + srow) * K + kbeg + scol;
  f32x4 acc[2][4] = {};
  int nk = klen >> 6;
#pragma unroll
  for (int i = 0; i < 2; ++i) {
    gload_lds16(Ab + (size_t)i * 8 * K, &As[(w * 16 + i * 8) * 64]);
    gload_lds16(Wb + (size_t)i * 8 * K, &Bs[(w * 16 + i * 8) * 64]);
  }
  __syncthreads();
  for (int t = 0; t < nk; ++t) {
    int cur = t & 1;
    if (t + 1 < nk) {
      int ko = (t + 1) * 64;
#pragma unroll
      for (int i = 0; i < 2; ++i) {
        gload_lds16(Ab + (size_t)i * 8 * K + ko,
                    &As[(cur ^ 1) * 8192 + (w * 16 + i * 8) * 64]);
        gload_lds16(Wb + (size_t)i * 8 * K + ko,
                    &Bs[(cur ^ 1) * 8192 + (w * 16 + i * 8) * 64]);
      }
    }
#pragma unroll
    for (int kk = 0; kk < 2; ++kk) {
      bf16x8 af[2], bfr[4];
#pragma unroll
      for (int f = 0; f < 2; ++f) {
        int ra = wm + f * 16 + q;
        af[f] = *(const bf16x8*)(&As[cur * 8192 + ra * 64 + ((kk * 4 + g) ^ (ra & 7)) * 8]);
      }
#pragma unroll
      for (int f = 0; f < 4; ++f) {
        int rb = wn + f * 16 + q;
        bfr[f] = *(const bf16x8*)(&Bs[cur * 8192 + rb * 64 + ((kk * 4 + g) ^ (rb & 7)) * 8]);
      }
#pragma unroll
      for (int fm = 0; fm < 2; ++fm)
#pragma unroll
        for (int fn = 0; fn < 4; ++fn)
          acc[fm][fn] = __builtin_amdgcn_mfma_f32_16x16x32_bf16(af[fm], bfr[fn],
                                                                acc[fm][fn], 0, 0, 0);
    }
    __syncthreads();
  }
  if (EPI == 2) {
#pragma unroll
    for (int fm = 0; fm < 2; ++fm)
#pragma unroll
      for (int fn = 0; fn < 4; ++fn) {
        int gcol = bn + wn + fn * 16 + q;
        int growb = bm + wm + fm * 16 + g * 4;
        float bv = bias[gcol];
#pragma unroll
        for (int r = 0; r < 4; ++r)
          of[(size_t)(growb + r) * N + gcol] = res[(size_t)(growb + r) * N + gcol]
                                               + acc[fm][fn][r] + bv;
      }
    return;
  }
  bool tr = (EPI == 0 && z == 2);
#pragma unroll
  for (int fm = 0; fm < 2; ++fm) {
#pragma unroll
    for (int fn = 0; fn < 4; ++fn) {
      int cL = wn + fn * 16 + q;
      float bv = (EPI == 3) ? 0.0f : bias[bn + cL];
#pragma unroll
      for (int r = 0; r < 4; ++r) {
        int rL = wm + fm * 16 + g * 4 + r;
        float v = acc[fm][fn][r] + bv;
        if (EPI == 0 && z == 0) v *= 0.125f;
        if (tr) Cs[cL * 132 + rL] = f2b(v);
        else    Cs[rL * 132 + cL] = f2b(v);
      }
    }
  }
  __syncthreads();
  {
    int rowL = tid >> 4, c8 = (tid & 15) * 8;
#pragma unroll
    for (int p = 0; p < 4; ++p) {
      int row = p * 32 + rowL;
      u16x4 lo = *(const u16x4*)(&Cs[row * 132 + c8]);
      u16x4 hi = *(const u16x4*)(&Cs[row * 132 + c8 + 4]);
      u16x8 ov = {lo[0], lo[1], lo[2], lo[3], hi[0], hi[1], hi[2], hi[3]};
      if (tr) {
        *(u16x8*)(o2t + (size_t)(bn + row) * M + bm + c8) = ov;
      } else if (EPI == 3) {
        *(u16x8*)(op + (size_t)z * M * N + (size_t)(bm + row) * N + bn + c8) = ov;
      } else {
        *(u16x8*)(outb + (size_t)(bm + row) * N + bn + c8) = ov;
      }
    }
  }
}

// ---------- GEMM 256x128: 512 thr / 8 waves (wave=64x64, acc[4][4]), BK=64 dbuf ----------
// 32 MFMA/wave/K-step — 2x compute density to amortize the per-step barrier drain.
// EPI 1: bf16 out + bias + exact GELU ; EPI 3: bf16 raw partial (split-K)
template <int EPI>
__global__ __launch_bounds__(512) void gemm256_k(
    const u16* __restrict__ A, const u16* __restrict__ Wt,
    const float* __restrict__ b0, u16* __restrict__ o0, u16* __restrict__ op,
    int M, int N, int K, int KS) {
  int z = blockIdx.z;
  int gx = gridDim.x, nwg = gx * gridDim.y;
  int lin = blockIdx.y * gx + blockIdx.x;
  int cpx = nwg >> 3;
  int swz = (lin & 7) * cpx + (lin >> 3);
  int bm = (swz % gx) * 256, bn = (swz / gx) * 128;
  int kbeg = (EPI == 3) ? z * KS : 0;
  int klen = (EPI == 3) ? KS : K;
  __shared__ __attribute__((aligned(16))) u16 SM[49152];  // 96 KB
  u16* As = SM;            // [2][256*64]
  u16* Bs = SM + 32768;    // [2][128*64]
  u16* Cs = SM;            // [256*132] epilogue staging
  int tid = threadIdx.x, l = tid & 63, w = tid >> 6;
  int q = l & 15, g = l >> 4;
  int wm = (w >> 1) * 64, wn = (w & 1) * 64;
  int srowA = w * 32 + (l >> 3);   // + i*8, i<4
  int srowB = w * 16 + (l >> 3);   // + i*8, i<2
  int scol = (((l & 7) ^ ((l >> 3) & 7))) * 8;
  const u16* Ab = A + (size_t)(bm + srowA) * K + kbeg + scol;
  const u16* Wb = Wt + (size_t)(bn + srowB) * K + kbeg + scol;
  f32x4 acc[4][4] = {};
  int nk = klen >> 6;
#define STG256(buf, ko)                                                       \
  {                                                                           \
    _Pragma("unroll") for (int i = 0; i < 4; ++i)                             \
        gload_lds16(Ab + (size_t)(i * 8) * K + (ko),                          \
                    &As[(buf) * 16384 + (w * 32 + i * 8) * 64]);              \
    _Pragma("unroll") for (int i = 0; i < 2; ++i)                             \
        gload_lds16(Wb + (size_t)(i * 8) * K + (ko),                          \
                    &Bs[(buf) * 8192 + (w * 16 + i * 8) * 64]);               \
  }
  STG256(0, 0);
  __syncthreads();
  for (int t = 0; t < nk; ++t) {
    int cur = t & 1;
    if (t + 1 < nk) STG256(cur ^ 1, (t + 1) * 64);
#pragma unroll
    for (int kk = 0; kk < 2; ++kk) {
      bf16x8 af[4], bfr[4];
#pragma unroll
      for (int f = 0; f < 4; ++f) {
        int ra = wm + f * 16 + q;
        af[f] = *(const bf16x8*)(&As[cur * 16384 + ra * 64 + ((kk * 4 + g) ^ (ra & 7)) * 8]);
        int rb = wn + f * 16 + q;
        bfr[f] = *(const bf16x8*)(&Bs[cur * 8192 + rb * 64 + ((kk * 4 + g) ^ (rb & 7)) * 8]);
      }
#pragma unroll
      for (int fm = 0; fm < 4; ++fm)
#pragma unroll
        for (int fn = 0; fn < 4; ++fn)
          acc[fm][fn] = __builtin_amdgcn_mfma_f32_16x16x32_bf16(af[fm], bfr[fn],
                                                                acc[fm][fn], 0, 0, 0);
    }
    __syncthreads();
  }
#undef STG256
  // staged epilogue
#pragma unroll
  for (int fm = 0; fm < 4; ++fm) {
#pragma unroll
    for (int fn = 0; fn < 4; ++fn) {
      int cL = wn + fn * 16 + q;
      float bv = (EPI == 3) ? 0.0f : b0[bn + cL];
#pragma unroll
      for (int r = 0; r < 4; ++r) {
        int rL = wm + fm * 16 + g * 4 + r;
        float v = acc[fm][fn][r] + bv;
        if (EPI == 1) v = 0.5f * v * (1.0f + erff(v * 0.70710678118f));
        Cs[rL * 132 + cL] = f2b(v);
      }
    }
  }
  __syncthreads();
  {
    int rowL = tid >> 4, c8 = (tid & 15) * 8;
#pragma unroll
    for (int p = 0; p < 8; ++p) {
      int row = p * 32 + rowL;
      u16x4 lo = *(const u16x4*)(&Cs[row * 132 + c8]);
      u16x4 hi = *(const u16x4*)(&Cs[row * 132 + c8 + 4]);
      u16x8 ov = {lo[0], lo[1], lo[2], lo[3], hi[0], hi[1], hi[2], hi[3]};
      if (EPI == 3) {
        *(u16x8*)(op + (size_t)z * M * N + (size_t)(bm + row) * N + bn + c8) = ov;
      } else {
        *(u16x8*)(o0 + (size_t)(bm + row) * N + bn + c8) = ov;
      }
    }
  }
}

// ---------- flash attention; KVBLK=64, defer-max, Q pre-scaled; V^T input ----------
__global__ __launch_bounds__(256) void attn_k(const u16* __restrict__ Q,
                                              const u16* __restrict__ Kb,
                                              const u16* __restrict__ Vt,
                                              u16* __restrict__ O) {
  int bid = blockIdx.x;                       // 512 = qt(16) | h(16) | b(2)
  int qt = bid & 15, h = (bid >> 4) & 15, b = bid >> 8;
  int tid = threadIdx.x, l = tid & 63, w = tid >> 6;
  int q = l & 15, g = l >> 4;
  int tokbase = b * TT;
  int qbase = tokbase + qt * 64 + w * 16;
  __shared__ __attribute__((aligned(16))) u16 Ks[2][64 * 64];
  __shared__ __attribute__((aligned(16))) u16 Vs[2][64 * 64];
  __shared__ __attribute__((aligned(16))) u16 Ps[4][1024];
  bf16x8 qf[2];
  {
    int qrow = qbase + q;
#pragma unroll
    for (int half = 0; half < 2; ++half)
      qf[half] = *(const bf16x8*)(Q + (size_t)qrow * DV + h * 64 + half * 32 + g * 8);
  }
  int rr = tid >> 3, cc = tid & 7;
  const u16* ksrc = Kb + (size_t)(tokbase + rr) * DV + h * 64 + ((cc ^ (rr & 7)) * 8);
  const u16* vsrc = Vt + (size_t)(h * 64 + rr) * NTOK + tokbase + ((cc ^ (rr & 7)) * 8);
  const size_t kst = (size_t)32 * DV;
  const size_t vst = (size_t)32 * NTOK;
  f32x4 oacc[4] = {};
  float m_run = -INFINITY, l_run = 0.0f;
#define AST(bb_, t)                                                      \
  {                                                                      \
    gload_lds16(ksrc + (size_t)(t) * 64 * DV, &Ks[bb_][tid * 8]);        \
    gload_lds16(ksrc + (size_t)(t) * 64 * DV + kst, &Ks[bb_][2048 + tid * 8]); \
    gload_lds16(vsrc + (t) * 64, &Vs[bb_][tid * 8]);                     \
    gload_lds16(vsrc + (t) * 64 + vst, &Vs[bb_][2048 + tid * 8]);        \
  }
  AST(0, 0);
  __syncthreads();
  const int nkb = TT / 64;
  for (int kbk = 0; kbk < nkb; ++kbk) {
    int cur = kbk & 1;
    if (kbk + 1 < nkb) AST(cur ^ 1, kbk + 1);
    f32x4 s[4] = {};
#pragma unroll
    for (int kt = 0; kt < 4; ++kt) {
      int row = kt * 16 + q;
#pragma unroll
      for (int half = 0; half < 2; ++half) {
        int chunk = (half * 4 + g) ^ (row & 7);
        bf16x8 kf = *(const bf16x8*)(&Ks[cur][row * 64 + chunk * 8]);
        s[kt] = __builtin_amdgcn_mfma_f32_16x16x32_bf16(kf, qf[half], s[kt], 0, 0, 0);
      }
    }
    float tmax = -INFINITY;
#pragma unroll
    for (int kt = 0; kt < 4; ++kt)
#pragma unroll
      for (int r = 0; r < 4; ++r) tmax = fmaxf(tmax, s[kt][r]);
    tmax = fmaxf(tmax, __shfl_xor(tmax, 16));
    tmax = fmaxf(tmax, __shfl_xor(tmax, 32));
    if (!__all(tmax <= m_run + 8.0f)) {
      float m_new = fmaxf(m_run, tmax);
      float corr = __expf(m_run - m_new);
      float corr4[4];
#pragma unroll
      for (int r = 0; r < 4; ++r) corr4[r] = __shfl(corr, g * 4 + r);
#pragma unroll
      for (int nt = 0; nt < 4; ++nt)
#pragma unroll
        for (int r = 0; r < 4; ++r) oacc[nt][r] *= corr4[r];
      l_run *= corr;
      m_run = m_new;
    }
    float psum = 0.0f;
    u16x4 pb[4];
#pragma unroll
    for (int kt = 0; kt < 4; ++kt)
#pragma unroll
      for (int r = 0; r < 4; ++r) {
        float p = __expf(s[kt][r] - m_run);
        psum += p;
        pb[kt][r] = f2b(p);
      }
    psum += __shfl_xor(psum, 16);
    psum += __shfl_xor(psum, 32);
    l_run += psum;
#pragma unroll
    for (int kt = 0; kt < 4; ++kt)
      *(u16x4*)(&Ps[w][q * 64 + ((kt * 4 + g) ^ (q & 7)) * 4]) = pb[kt];
#pragma unroll
    for (int kt2 = 0; kt2 < 2; ++kt2) {
      int c0 = kt2 * 8 + (g >> 1) * 4 + (g & 1) * 2;
      u16x4 a0 = *(const u16x4*)(&Ps[w][q * 64 + ((c0) ^ (q & 7)) * 4]);
      u16x4 a1 = *(const u16x4*)(&Ps[w][q * 64 + ((c0 + 1) ^ (q & 7)) * 4]);
      bf16x8 pa = {(short)a0[0], (short)a0[1], (short)a0[2], (short)a0[3],
                   (short)a1[0], (short)a1[1], (short)a1[2], (short)a1[3]};
#pragma unroll
      for (int nt = 0; nt < 4; ++nt) {
        int vrow = nt * 16 + q;
        int vc = (kt2 * 4 + g) ^ (vrow & 7);
        bf16x8 vf = *(const bf16x8*)(&Vs[cur][vrow * 64 + vc * 8]);
        oacc[nt] = __builtin_amdgcn_mfma_f32_16x16x32_bf16(pa, vf, oacc[nt], 0, 0, 0);
      }
    }
    __syncthreads();
  }
#undef AST
  float rl[4];
#pragma unroll
  for (int r = 0; r < 4; ++r) rl[r] = 1.0f / __shfl(l_run, g * 4 + r);
#pragma unroll
  for (int nt = 0; nt < 4; ++nt)
#pragma unroll
    for (int r = 0; r < 4; ++r) {
      int qrw = qbase + g * 4 + r;
      int d = nt * 16 + q;
      O[(size_t)qrw * DV + h * 64 + d] = f2b(oacc[nt][r] * rl[r]);
    }
}

extern "C" void kernel_launch(void* const* d_in, const int* in_sizes, int n_in,
                              void* d_out, int out_size, void* d_ws, size_t ws_size,
                              hipStream_t stream) {
  const int*   ids = (const int*)d_in[0];
  const float* wte = (const float*)d_in[1];
  const float* wpe = (const float*)d_in[2];
  const float* l1g = (const float*)d_in[3];
  const float* l1b = (const float*)d_in[4];
  const float* wq  = (const float*)d_in[5];
  const float* bq  = (const float*)d_in[6];
  const float* wk  = (const float*)d_in[7];
  const float* bk  = (const float*)d_in[8];
  const float* wv  = (const float*)d_in[9];
  const float* bv  = (const float*)d_in[10];
  const float* wo  = (const float*)d_in[11];
  const float* bo  = (const float*)d_in[12];
  const float* l2g = (const float*)d_in[13];
  const float* l2b = (const float*)d_in[14];
  const float* w1  = (const float*)d_in[15];
  const float* b1  = (const float*)d_in[16];
  const float* w2  = (const float*)d_in[17];
  const float* b2  = (const float*)d_in[18];
  const float* lfg = (const float*)d_in[19];
  const float* lfb = (const float*)d_in[20];
  (void)in_sizes; (void)n_in; (void)out_size;

  bool bigws = ws_size >= ((size_t)221 << 20);
  bool midws = ws_size >= ((size_t)101 << 20);

  char* ws = (char*)d_ws;
  float* x   = (float*)(ws + 0);                 // 8 MB residual (f32)
  u16*   hb  = (u16*)(ws + ((size_t)8 << 20));   // 4 MB LN out
  u16*   qb  = (u16*)(ws + ((size_t)12 << 20));  // 4 MB (pre-scaled 0.125)
  u16*   kb  = (u16*)(ws + ((size_t)16 << 20));  // 4 MB
  u16*   vbt = (u16*)(ws + ((size_t)20 << 20));  // 4 MB V^T [D][tok]
  u16*   ab  = (u16*)(ws + ((size_t)24 << 20));  // 4 MB attn out
  u16*   mb  = (u16*)(ws + ((size_t)28 << 20));  // 16 MB gelu out
  u16*   pp  = (u16*)(ws + ((size_t)44 << 20));  // 16 MB bf16 partials
  u16*   WT  = (u16*)(ws + ((size_t)(midws ? 76 : 44) << 20));

  if (bigws)
    transw_k<<<dim3(768, 6), 256, 0, stream>>>(wq, wk, wv, wo, w1, w2, WT);
  embed_ln_k<<<NTOK, 256, 0, stream>>>(ids, wte, wpe, l1g, l1b, x, hb);

  for (int lay = 0; lay < NLAY; ++lay) {
    size_t oDD = (size_t)lay * DV * DV;
    size_t oDF = (size_t)lay * DV * FF;
    u16* WTL = bigws ? WT + (size_t)lay * 12 * 1024 * 1024 : WT;
    if (!bigws)
      transw_k<<<dim3(768, 1), 256, 0, stream>>>(wq + oDD, wk + oDD, wv + oDD,
                                                 wo + oDD, w1 + oDF, w2 + oDF, WTL);
    gemm_k<0><<<dim3(16, 8, 3), 512, 0, stream>>>(
        hb, WTL, bq + lay * DV, bk + lay * DV, bv + lay * DV,
        qb, kb, vbt, nullptr, nullptr, nullptr, NTOK, DV, DV, 0);
    attn_k<<<512, 256, 0, stream>>>(qb, kb, vbt, ab);
    if (midws) {
      gemm_k<3><<<dim3(16, 8, 2), 512, 0, stream>>>(
          ab, WTL + (size_t)3 * DV * DV, nullptr, nullptr, nullptr,
          nullptr, nullptr, nullptr, pp, nullptr, nullptr, NTOK, DV, DV, 512);
      reduce_ln_k<2, 0><<<NTOK, 256, 0, stream>>>(
          x, pp, bo + lay * DV, l2g + lay * DV, l2b + lay * DV, hb, nullptr);
    } else {
      gemm_k<2><<<dim3(16, 8, 1), 512, 0, stream>>>(
          ab, WTL + (size_t)3 * DV * DV, bo + lay * DV, nullptr, nullptr,
          nullptr, nullptr, nullptr, nullptr, x, x, NTOK, DV, DV, 0);
      ln_k<0><<<NTOK, 256, 0, stream>>>(x, l2g + lay * DV, l2b + lay * DV, hb, nullptr);
    }
    gemm256_k<1><<<dim3(8, 32), 512, 0, stream>>>(
        hb, WTL + (size_t)4 * DV * DV, b1 + lay * FF, mb, nullptr,
        NTOK, FF, DV, 0);
    if (midws) {
      gemm256_k<3><<<dim3(8, 8, 4), 512, 0, stream>>>(
          mb, WTL + (size_t)8 * DV * DV, nullptr, nullptr, pp,
          NTOK, DV, FF, 1024);
      if (lay < NLAY - 1)
        reduce_ln_k<4, 0><<<NTOK, 256, 0, stream>>>(
            x, pp, b2 + lay * DV, l1g + (lay + 1) * DV, l1b + (lay + 1) * DV,
            hb, nullptr);
      else
        reduce_ln_k<4, 1><<<NTOK, 256, 0, stream>>>(
            x, pp, b2 + lay * DV, lfg, lfb, nullptr, (float*)d_out);
    } else {
      gemm_k<2><<<dim3(16, 8, 1), 512, 0, stream>>>(
          mb, WTL + (size_t)8 * DV * DV, b2 + lay * DV, nullptr, nullptr,
          nullptr, nullptr, nullptr, nullptr, x, x, NTOK, DV, FF, 0);
      if (lay < NLAY - 1)
        ln_k<0><<<NTOK, 256, 0, stream>>>(x, l1g + (lay + 1) * DV,
                                          l1b + (lay + 1) * DV, hb, nullptr);
      else
        ln_k<1><<<NTOK, 256, 0, stream>>>(x, lfg, lfb, nullptr, (float*)d_out);
    }
  }
}

// Round 13
// 861.786 us; speedup vs baseline: 1.0461x; 1.0461x over previous
//
#include <hip/hip_runtime.h>
#include <hip/hip_bf16.h>
#include <math.h>

#define DV 1024
#define FF 4096
#define NLAY 6
#define NH 16
#define TT 1024
#define NTOK 2048

typedef float f32x4 __attribute__((ext_vector_type(4)));
typedef short bf16x8 __attribute__((ext_vector_type(8)));
typedef unsigned short u16;
typedef u16 u16x4 __attribute__((ext_vector_type(4)));
typedef u16 u16x8 __attribute__((ext_vector_type(8)));

__device__ __forceinline__ u16 f2b(float f) {
  unsigned u = __float_as_uint(f);
  unsigned r = (u + 0x7fffu + ((u >> 16) & 1u)) >> 16;  // RNE, finite inputs
  return (u16)r;
}
__device__ __forceinline__ float b2f(u16 u) {
  return __uint_as_float(((unsigned)u) << 16);
}

__device__ __forceinline__ void gload_lds16(const void* g, void* lds) {
  __builtin_amdgcn_global_load_lds(
      (const __attribute__((address_space(1))) void*)g,
      (__attribute__((address_space(3))) void*)lds, 16, 0, 0);
}

// ---------- embed + LN1(layer0) fused ----------
__global__ __launch_bounds__(256) void embed_ln_k(const int* __restrict__ ids,
                                                  const float* __restrict__ wte,
                                                  const float* __restrict__ wpe,
                                                  const float* __restrict__ gg,
                                                  const float* __restrict__ bb,
                                                  float* __restrict__ X,
                                                  u16* __restrict__ outb) {
  int row = blockIdx.x, tid = threadIdx.x;
  int t = row & (TT - 1);
  int id = ids[row];
  f32x4 a = *(const f32x4*)(wte + (size_t)id * DV + tid * 4);
  f32x4 p = *(const f32x4*)(wpe + (size_t)t * DV + tid * 4);
  f32x4 v = a + p;
  *(f32x4*)(X + (size_t)row * DV + tid * 4) = v;
  float s1 = v[0] + v[1] + v[2] + v[3];
  float s2 = v[0] * v[0] + v[1] * v[1] + v[2] * v[2] + v[3] * v[3];
#pragma unroll
  for (int o = 32; o >= 1; o >>= 1) {
    s1 += __shfl_xor(s1, o);
    s2 += __shfl_xor(s2, o);
  }
  __shared__ float sh[8];
  int w = tid >> 6;
  if ((tid & 63) == 0) { sh[w] = s1; sh[w + 4] = s2; }
  __syncthreads();
  s1 = sh[0] + sh[1] + sh[2] + sh[3];
  s2 = sh[4] + sh[5] + sh[6] + sh[7];
  float mean = s1 * (1.0f / DV);
  float var = s2 * (1.0f / DV) - mean * mean;
  float rstd = rsqrtf(var + 1e-5f);
  f32x4 gv = *(const f32x4*)(gg + tid * 4);
  f32x4 bv = *(const f32x4*)(bb + tid * 4);
  u16x4 r;
#pragma unroll
  for (int i = 0; i < 4; ++i) r[i] = f2b((v[i] - mean) * rstd * gv[i] + bv[i]);
  *(u16x4*)(outb + (size_t)row * DV + tid * 4) = r;
}

// ---------- plain LN (fallback path) ----------
template <int OUTF>
__global__ __launch_bounds__(256) void ln_k(const float* __restrict__ X,
                                            const float* __restrict__ gg,
                                            const float* __restrict__ bb,
                                            u16* __restrict__ outb,
                                            float* __restrict__ outf) {
  int row = blockIdx.x, tid = threadIdx.x;
  f32x4 v = *(const f32x4*)(X + (size_t)row * DV + tid * 4);
  float s1 = v[0] + v[1] + v[2] + v[3];
  float s2 = v[0] * v[0] + v[1] * v[1] + v[2] * v[2] + v[3] * v[3];
#pragma unroll
  for (int o = 32; o >= 1; o >>= 1) {
    s1 += __shfl_xor(s1, o);
    s2 += __shfl_xor(s2, o);
  }
  __shared__ float sh[8];
  int w = tid >> 6;
  if ((tid & 63) == 0) { sh[w] = s1; sh[w + 4] = s2; }
  __syncthreads();
  s1 = sh[0] + sh[1] + sh[2] + sh[3];
  s2 = sh[4] + sh[5] + sh[6] + sh[7];
  float mean = s1 * (1.0f / DV);
  float var = s2 * (1.0f / DV) - mean * mean;
  float rstd = rsqrtf(var + 1e-5f);
  f32x4 gv = *(const f32x4*)(gg + tid * 4);
  f32x4 bv = *(const f32x4*)(bb + tid * 4);
  f32x4 o;
#pragma unroll
  for (int i = 0; i < 4; ++i) o[i] = (v[i] - mean) * rstd * gv[i] + bv[i];
  if (OUTF) {
    *(f32x4*)(outf + (size_t)row * DV + tid * 4) = o;
  } else {
    u16x4 r = {f2b(o[0]), f2b(o[1]), f2b(o[2]), f2b(o[3])};
    *(u16x4*)(outb + (size_t)row * DV + tid * 4) = r;
  }
}

// ---------- fused: x += bias + sum(bf16 partials); LN(x) ----------
template <int NS, int OUTF>
__global__ __launch_bounds__(256) void reduce_ln_k(
    float* __restrict__ X, const u16* __restrict__ pp,
    const float* __restrict__ bias, const float* __restrict__ gg,
    const float* __restrict__ bb, u16* __restrict__ outb,
    float* __restrict__ outf) {
  int row = blockIdx.x, tid = threadIdx.x;
  size_t off = (size_t)row * DV + tid * 4;
  f32x4 v = *(const f32x4*)(X + off);
  if (NS > 0) {
    f32x4 bvv = *(const f32x4*)(bias + tid * 4);
    v += bvv;
#pragma unroll
    for (int s = 0; s < NS; ++s) {
      u16x4 pv = *(const u16x4*)(pp + (size_t)s * NTOK * DV + off);
      v[0] += b2f(pv[0]); v[1] += b2f(pv[1]);
      v[2] += b2f(pv[2]); v[3] += b2f(pv[3]);
    }
    *(f32x4*)(X + off) = v;
  }
  float s1 = v[0] + v[1] + v[2] + v[3];
  float s2 = v[0] * v[0] + v[1] * v[1] + v[2] * v[2] + v[3] * v[3];
#pragma unroll
  for (int o = 32; o >= 1; o >>= 1) {
    s1 += __shfl_xor(s1, o);
    s2 += __shfl_xor(s2, o);
  }
  __shared__ float sh[8];
  int w = tid >> 6;
  if ((tid & 63) == 0) { sh[w] = s1; sh[w + 4] = s2; }
  __syncthreads();
  s1 = sh[0] + sh[1] + sh[2] + sh[3];
  s2 = sh[4] + sh[5] + sh[6] + sh[7];
  float mean = s1 * (1.0f / DV);
  float var = s2 * (1.0f / DV) - mean * mean;
  float rstd = rsqrtf(var + 1e-5f);
  f32x4 gv = *(const f32x4*)(gg + tid * 4);
  f32x4 bv = *(const f32x4*)(bb + tid * 4);
  f32x4 o;
#pragma unroll
  for (int i = 0; i < 4; ++i) o[i] = (v[i] - mean) * rstd * gv[i] + bv[i];
  if (OUTF) {
    *(f32x4*)(outf + off) = o;
  } else {
    u16x4 r = {f2b(o[0]), f2b(o[1]), f2b(o[2]), f2b(o[3])};
    *(u16x4*)(outb + off) = r;
  }
}

// ---------- weight transpose: W[K][N] f32 -> WT[N][K] bf16 (retired from tuning) ----------
__global__ __launch_bounds__(256) void transw_k(const float* __restrict__ wq,
                                                const float* __restrict__ wk,
                                                const float* __restrict__ wv,
                                                const float* __restrict__ wo,
                                                const float* __restrict__ w1,
                                                const float* __restrict__ w2,
                                                u16* __restrict__ WT) {
  int lay = blockIdx.y;
  size_t oDD = (size_t)lay * DV * DV, oDF = (size_t)lay * DV * FF;
  u16* WTL = WT + (size_t)lay * 12 * 1024 * 1024;
  int bid = blockIdx.x;
  const float* src;
  u16* dst;
  int K, N, tile;
  if (bid < 256) {
    int which = bid >> 6;
    src = (which == 0 ? wq : which == 1 ? wk : which == 2 ? wv : wo) + oDD;
    dst = WTL + (size_t)which * (DV * DV);
    K = DV; N = DV; tile = bid & 63;
  } else if (bid < 512) {
    src = w1 + oDF; dst = WTL + (size_t)4 * (DV * DV); K = DV; N = FF; tile = bid - 256;
  } else {
    src = w2 + oDF; dst = WTL + (size_t)8 * (DV * DV); K = FF; N = DV; tile = bid - 512;
  }
  int ntc = N >> 8;
  int tr = tile / ntc, tc = tile - tr * ntc;
  int k0 = tr * 64, n0 = tc * 256;
  __shared__ u16 ts[64][258];
  int tid = threadIdx.x, l = tid & 63, w = tid >> 6;
  f32x4 vv[16];
#pragma unroll
  for (int i = 0; i < 16; ++i)
    vv[i] = *(const f32x4*)(src + (size_t)(k0 + i * 4 + w) * N + n0 + l * 4);
#pragma unroll
  for (int i = 0; i < 16; ++i) {
    u16x4 c = {f2b(vv[i][0]), f2b(vv[i][1]), f2b(vv[i][2]), f2b(vv[i][3])};
    *(u16x4*)(&ts[i * 4 + w][l * 4]) = c;
  }
  __syncthreads();
  int kk = (tid & 7) * 8, nn = tid >> 3;
#pragma unroll
  for (int j = 0; j < 8; ++j) {
    int n = j * 32 + nn;
    u16x8 ov;
#pragma unroll
    for (int m = 0; m < 8; ++m) ov[m] = ts[kk + m][n];
    *(u16x8*)(dst + (size_t)(n0 + n) * K + k0 + kk) = ov;
  }
}

// ---------- GEMM 128x128: 512 thr / 8 waves, BK=64 dbuf, T2 swizzle ----------
// (R10 structure — measured best; R4/R5 pipelines and R11 256-tile refuted.)
// EPI 0: bf16 out + bias; z==0 -> o0 SCALED 0.125 (Q); z==1 -> o1; z==2 -> b2v, TRANSPOSED o2t
// EPI 1: bf16 out + bias + exact GELU
// EPI 2: f32 out = res + C + bias (fallback, unstaged)
// EPI 3: bf16 raw partial to op + z*M*N, K range [z*KS,(z+1)*KS)
template <int EPI>
__global__ __launch_bounds__(512) void gemm_k(
    const u16* __restrict__ A, const u16* __restrict__ Wt,
    const float* __restrict__ b0, const float* __restrict__ b1,
    const float* __restrict__ b2v, u16* __restrict__ o0, u16* __restrict__ o1,
    u16* __restrict__ o2t, u16* __restrict__ op, float* __restrict__ of,
    const float* __restrict__ res, int M, int N, int K, int KS) {
  int z = blockIdx.z;
  const u16* W = Wt;
  const float* bias = b0;
  u16* outb = o0;
  if (EPI == 0) {
    W = Wt + (size_t)z * N * K;
    bias = z == 0 ? b0 : z == 1 ? b1 : b2v;
    outb = z == 0 ? o0 : o1;
  }
  int gx = gridDim.x, nwg = gx * gridDim.y;
  int lin = blockIdx.y * gx + blockIdx.x;
  int cpx = nwg >> 3;
  int swz = (lin & 7) * cpx + (lin >> 3);
  int bm = (swz % gx) * 128, bn = (swz / gx) * 128;
  int kbeg = (EPI == 3) ? z * KS : 0;
  int klen = (EPI == 3) ? KS : K;
  __shared__ __attribute__((aligned(16))) u16 SM[32768];  // 64 KB
  u16* As = SM;
  u16* Bs = SM + 16384;
  u16* Cs = SM;
  int tid = threadIdx.x, l = tid & 63, w = tid >> 6;
  int q = l & 15, g = l >> 4;
  int wm = (w >> 1) * 32, wn = (w & 1) * 64;
  int srow = w * 16 + (l >> 3);
  int scol = (((l & 7) ^ ((l >> 3) & 7))) * 8;
  const u16* Ab = A + (size_t)(bm + srow) * K + kbeg + scol;
  const u16* Wb = W + (size_t)(bn + srow) * K + kbeg + scol;
  f32x4 acc[2][4] = {};
  int nk = klen >> 6;
#pragma unroll
  for (int i = 0; i < 2; ++i) {
    gload_lds16(Ab + (size_t)i * 8 * K, &As[(w * 16 + i * 8) * 64]);
    gload_lds16(Wb + (size_t)i * 8 * K, &Bs[(w * 16 + i * 8) * 64]);
  }
  __syncthreads();
  for (int t = 0; t < nk; ++t) {
    int cur = t & 1;
    if (t + 1 < nk) {
      int ko = (t + 1) * 64;
#pragma unroll
      for (int i = 0; i < 2; ++i) {
        gload_lds16(Ab + (size_t)i * 8 * K + ko,
                    &As[(cur ^ 1) * 8192 + (w * 16 + i * 8) * 64]);
        gload_lds16(Wb + (size_t)i * 8 * K + ko,
                    &Bs[(cur ^ 1) * 8192 + (w * 16 + i * 8) * 64]);
      }
    }
#pragma unroll
    for (int kk = 0; kk < 2; ++kk) {
      bf16x8 af[2], bfr[4];
#pragma unroll
      for (int f = 0; f < 2; ++f) {
        int ra = wm + f * 16 + q;
        af[f] = *(const bf16x8*)(&As[cur * 8192 + ra * 64 + ((kk * 4 + g) ^ (ra & 7)) * 8]);
      }
#pragma unroll
      for (int f = 0; f < 4; ++f) {
        int rb = wn + f * 16 + q;
        bfr[f] = *(const bf16x8*)(&Bs[cur * 8192 + rb * 64 + ((kk * 4 + g) ^ (rb & 7)) * 8]);
      }
#pragma unroll
      for (int fm = 0; fm < 2; ++fm)
#pragma unroll
        for (int fn = 0; fn < 4; ++fn)
          acc[fm][fn] = __builtin_amdgcn_mfma_f32_16x16x32_bf16(af[fm], bfr[fn],
                                                                acc[fm][fn], 0, 0, 0);
    }
    __syncthreads();
  }
  if (EPI == 2) {
#pragma unroll
    for (int fm = 0; fm < 2; ++fm)
#pragma unroll
      for (int fn = 0; fn < 4; ++fn) {
        int gcol = bn + wn + fn * 16 + q;
        int growb = bm + wm + fm * 16 + g * 4;
        float bv = bias[gcol];
#pragma unroll
        for (int r = 0; r < 4; ++r)
          of[(size_t)(growb + r) * N + gcol] = res[(size_t)(growb + r) * N + gcol]
                                               + acc[fm][fn][r] + bv;
      }
    return;
  }
  bool tr = (EPI == 0 && z == 2);
#pragma unroll
  for (int fm = 0; fm < 2; ++fm) {
#pragma unroll
    for (int fn = 0; fn < 4; ++fn) {
      int cL = wn + fn * 16 + q;
      float bv = (EPI == 3) ? 0.0f : bias[bn + cL];
#pragma unroll
      for (int r = 0; r < 4; ++r) {
        int rL = wm + fm * 16 + g * 4 + r;
        float v = acc[fm][fn][r] + bv;
        if (EPI == 1) v = 0.5f * v * (1.0f + erff(v * 0.70710678118f));
        if (EPI == 0 && z == 0) v *= 0.125f;
        if (tr) Cs[cL * 132 + rL] = f2b(v);
        else    Cs[rL * 132 + cL] = f2b(v);
      }
    }
  }
  __syncthreads();
  {
    int rowL = tid >> 4, c8 = (tid & 15) * 8;
#pragma unroll
    for (int p = 0; p < 4; ++p) {
      int row = p * 32 + rowL;
      u16x4 lo = *(const u16x4*)(&Cs[row * 132 + c8]);
      u16x4 hi = *(const u16x4*)(&Cs[row * 132 + c8 + 4]);
      u16x8 ov = {lo[0], lo[1], lo[2], lo[3], hi[0], hi[1], hi[2], hi[3]};
      if (tr) {
        *(u16x8*)(o2t + (size_t)(bn + row) * M + bm + c8) = ov;
      } else if (EPI == 3) {
        *(u16x8*)(op + (size_t)z * M * N + (size_t)(bm + row) * N + bn + c8) = ov;
      } else {
        *(u16x8*)(outb + (size_t)(bm + row) * N + bn + c8) = ov;
      }
    }
  }
}

// ---------- flash attention; KVBLK=64, defer-max, Q pre-scaled; V^T input ----------
// XCD-affinity block swizzle: 16-block (h,b) groups land on one XCD's L2.
__global__ __launch_bounds__(256) void attn_k(const u16* __restrict__ Q,
                                              const u16* __restrict__ Kb,
                                              const u16* __restrict__ Vt,
                                              u16* __restrict__ O) {
  int hw = blockIdx.x;                        // 512 blocks, 512 % 8 == 0
  int bid = (hw & 7) * 64 + (hw >> 3);        // bijective; same-XCD hw ids -> same (h,b)
  int qt = bid & 15, h = (bid >> 4) & 15, b = bid >> 8;
  int tid = threadIdx.x, l = tid & 63, w = tid >> 6;
  int q = l & 15, g = l >> 4;
  int tokbase = b * TT;
  int qbase = tokbase + qt * 64 + w * 16;
  __shared__ __attribute__((aligned(16))) u16 Ks[2][64 * 64];
  __shared__ __attribute__((aligned(16))) u16 Vs[2][64 * 64];
  __shared__ __attribute__((aligned(16))) u16 Ps[4][1024];
  bf16x8 qf[2];
  {
    int qrow = qbase + q;
#pragma unroll
    for (int half = 0; half < 2; ++half)
      qf[half] = *(const bf16x8*)(Q + (size_t)qrow * DV + h * 64 + half * 32 + g * 8);
  }
  int rr = tid >> 3, cc = tid & 7;
  const u16* ksrc = Kb + (size_t)(tokbase + rr) * DV + h * 64 + ((cc ^ (rr & 7)) * 8);
  const u16* vsrc = Vt + (size_t)(h * 64 + rr) * NTOK + tokbase + ((cc ^ (rr & 7)) * 8);
  const size_t kst = (size_t)32 * DV;
  const size_t vst = (size_t)32 * NTOK;
  f32x4 oacc[4] = {};
  float m_run = -INFINITY, l_run = 0.0f;
#define AST(bb_, t)                                                      \
  {                                                                      \
    gload_lds16(ksrc + (size_t)(t) * 64 * DV, &Ks[bb_][tid * 8]);        \
    gload_lds16(ksrc + (size_t)(t) * 64 * DV + kst, &Ks[bb_][2048 + tid * 8]); \
    gload_lds16(vsrc + (t) * 64, &Vs[bb_][tid * 8]);                     \
    gload_lds16(vsrc + (t) * 64 + vst, &Vs[bb_][2048 + tid * 8]);        \
  }
  AST(0, 0);
  __syncthreads();
  const int nkb = TT / 64;
  for (int kbk = 0; kbk < nkb; ++kbk) {
    int cur = kbk & 1;
    if (kbk + 1 < nkb) AST(cur ^ 1, kbk + 1);
    f32x4 s[4] = {};
#pragma unroll
    for (int kt = 0; kt < 4; ++kt) {
      int row = kt * 16 + q;
#pragma unroll
      for (int half = 0; half < 2; ++half) {
        int chunk = (half * 4 + g) ^ (row & 7);
        bf16x8 kf = *(const bf16x8*)(&Ks[cur][row * 64 + chunk * 8]);
        s[kt] = __builtin_amdgcn_mfma_f32_16x16x32_bf16(kf, qf[half], s[kt], 0, 0, 0);
      }
    }
    float tmax = -INFINITY;
#pragma unroll
    for (int kt = 0; kt < 4; ++kt)
#pragma unroll
      for (int r = 0; r < 4; ++r) tmax = fmaxf(tmax, s[kt][r]);
    tmax = fmaxf(tmax, __shfl_xor(tmax, 16));
    tmax = fmaxf(tmax, __shfl_xor(tmax, 32));
    if (!__all(tmax <= m_run + 8.0f)) {
      float m_new = fmaxf(m_run, tmax);
      float corr = __expf(m_run - m_new);
      float corr4[4];
#pragma unroll
      for (int r = 0; r < 4; ++r) corr4[r] = __shfl(corr, g * 4 + r);
#pragma unroll
      for (int nt = 0; nt < 4; ++nt)
#pragma unroll
        for (int r = 0; r < 4; ++r) oacc[nt][r] *= corr4[r];
      l_run *= corr;
      m_run = m_new;
    }
    float psum = 0.0f;
    u16x4 pb[4];
#pragma unroll
    for (int kt = 0; kt < 4; ++kt)
#pragma unroll
      for (int r = 0; r < 4; ++r) {
        float p = __expf(s[kt][r] - m_run);
        psum += p;
        pb[kt][r] = f2b(p);
      }
    psum += __shfl_xor(psum, 16);
    psum += __shfl_xor(psum, 32);
    l_run += psum;
#pragma unroll
    for (int kt = 0; kt < 4; ++kt)
      *(u16x4*)(&Ps[w][q * 64 + ((kt * 4 + g) ^ (q & 7)) * 4]) = pb[kt];
#pragma unroll
    for (int kt2 = 0; kt2 < 2; ++kt2) {
      int c0 = kt2 * 8 + (g >> 1) * 4 + (g & 1) * 2;
      u16x4 a0 = *(const u16x4*)(&Ps[w][q * 64 + ((c0) ^ (q & 7)) * 4]);
      u16x4 a1 = *(const u16x4*)(&Ps[w][q * 64 + ((c0 + 1) ^ (q & 7)) * 4]);
      bf16x8 pa = {(short)a0[0], (short)a0[1], (short)a0[2], (short)a0[3],
                   (short)a1[0], (short)a1[1], (short)a1[2], (short)a1[3]};
#pragma unroll
      for (int nt = 0; nt < 4; ++nt) {
        int vrow = nt * 16 + q;
        int vc = (kt2 * 4 + g) ^ (vrow & 7);
        bf16x8 vf = *(const bf16x8*)(&Vs[cur][vrow * 64 + vc * 8]);
        oacc[nt] = __builtin_amdgcn_mfma_f32_16x16x32_bf16(pa, vf, oacc[nt], 0, 0, 0);
      }
    }
    __syncthreads();
  }
#undef AST
  float rl[4];
#pragma unroll
  for (int r = 0; r < 4; ++r) rl[r] = 1.0f / __shfl(l_run, g * 4 + r);
#pragma unroll
  for (int nt = 0; nt < 4; ++nt)
#pragma unroll
    for (int r = 0; r < 4; ++r) {
      int qrw = qbase + g * 4 + r;
      int d = nt * 16 + q;
      O[(size_t)qrw * DV + h * 64 + d] = f2b(oacc[nt][r] * rl[r]);
    }
}

extern "C" void kernel_launch(void* const* d_in, const int* in_sizes, int n_in,
                              void* d_out, int out_size, void* d_ws, size_t ws_size,
                              hipStream_t stream) {
  const int*   ids = (const int*)d_in[0];
  const float* wte = (const float*)d_in[1];
  const float* wpe = (const float*)d_in[2];
  const float* l1g = (const float*)d_in[3];
  const float* l1b = (const float*)d_in[4];
  const float* wq  = (const float*)d_in[5];
  const float* bq  = (const float*)d_in[6];
  const float* wk  = (const float*)d_in[7];
  const float* bk  = (const float*)d_in[8];
  const float* wv  = (const float*)d_in[9];
  const float* bv  = (const float*)d_in[10];
  const float* wo  = (const float*)d_in[11];
  const float* bo  = (const float*)d_in[12];
  const float* l2g = (const float*)d_in[13];
  const float* l2b = (const float*)d_in[14];
  const float* w1  = (const float*)d_in[15];
  const float* b1  = (const float*)d_in[16];
  const float* w2  = (const float*)d_in[17];
  const float* b2  = (const float*)d_in[18];
  const float* lfg = (const float*)d_in[19];
  const float* lfb = (const float*)d_in[20];
  (void)in_sizes; (void)n_in; (void)out_size;

  bool bigws = ws_size >= ((size_t)221 << 20);
  bool midws = ws_size >= ((size_t)101 << 20);

  char* ws = (char*)d_ws;
  float* x   = (float*)(ws + 0);                 // 8 MB residual (f32)
  u16*   hb  = (u16*)(ws + ((size_t)8 << 20));   // 4 MB LN out
  u16*   qb  = (u16*)(ws + ((size_t)12 << 20));  // 4 MB (pre-scaled 0.125)
  u16*   kb  = (u16*)(ws + ((size_t)16 << 20));  // 4 MB
  u16*   vbt = (u16*)(ws + ((size_t)20 << 20));  // 4 MB V^T [D][tok]
  u16*   ab  = (u16*)(ws + ((size_t)24 << 20));  // 4 MB attn out
  u16*   mb  = (u16*)(ws + ((size_t)28 << 20));  // 16 MB gelu out
  u16*   pp  = (u16*)(ws + ((size_t)44 << 20));  // 16 MB bf16 partials
  u16*   WT  = (u16*)(ws + ((size_t)(midws ? 76 : 44) << 20));

  if (bigws)
    transw_k<<<dim3(768, 6), 256, 0, stream>>>(wq, wk, wv, wo, w1, w2, WT);
  embed_ln_k<<<NTOK, 256, 0, stream>>>(ids, wte, wpe, l1g, l1b, x, hb);

  for (int lay = 0; lay < NLAY; ++lay) {
    size_t oDD = (size_t)lay * DV * DV;
    size_t oDF = (size_t)lay * DV * FF;
    u16* WTL = bigws ? WT + (size_t)lay * 12 * 1024 * 1024 : WT;
    if (!bigws)
      transw_k<<<dim3(768, 1), 256, 0, stream>>>(wq + oDD, wk + oDD, wv + oDD,
                                                 wo + oDD, w1 + oDF, w2 + oDF, WTL);
    gemm_k<0><<<dim3(16, 8, 3), 512, 0, stream>>>(
        hb, WTL, bq + lay * DV, bk + lay * DV, bv + lay * DV,
        qb, kb, vbt, nullptr, nullptr, nullptr, NTOK, DV, DV, 0);
    attn_k<<<512, 256, 0, stream>>>(qb, kb, vbt, ab);
    if (midws) {
      gemm_k<3><<<dim3(16, 8, 2), 512, 0, stream>>>(
          ab, WTL + (size_t)3 * DV * DV, nullptr, nullptr, nullptr,
          nullptr, nullptr, nullptr, pp, nullptr, nullptr, NTOK, DV, DV, 512);
      reduce_ln_k<2, 0><<<NTOK, 256, 0, stream>>>(
          x, pp, bo + lay * DV, l2g + lay * DV, l2b + lay * DV, hb, nullptr);
    } else {
      gemm_k<2><<<dim3(16, 8, 1), 512, 0, stream>>>(
          ab, WTL + (size_t)3 * DV * DV, bo + lay * DV, nullptr, nullptr,
          nullptr, nullptr, nullptr, nullptr, x, x, NTOK, DV, DV, 0);
      ln_k<0><<<NTOK, 256, 0, stream>>>(x, l2g + lay * DV, l2b + lay * DV, hb, nullptr);
    }
    gemm_k<1><<<dim3(16, 32, 1), 512, 0, stream>>>(
        hb, WTL + (size_t)4 * DV * DV, b1 + lay * FF, nullptr, nullptr,
        mb, nullptr, nullptr, nullptr, nullptr, nullptr, NTOK, FF, DV, 0);
    if (midws) {
      gemm_k<3><<<dim3(16, 8, 4), 512, 0, stream>>>(
          mb, WTL + (size_t)8 * DV * DV, nullptr, nullptr, nullptr,
          nullptr, nullptr, nullptr, pp, nullptr, nullptr, NTOK, DV, FF, 1024);
      if (lay < NLAY - 1)
        reduce_ln_k<4, 0><<<NTOK, 256, 0, stream>>>(
            x, pp, b2 + lay * DV, l1g + (lay + 1) * DV, l1b + (lay + 1) * DV,
            hb, nullptr);
      else
        reduce_ln_k<4, 1><<<NTOK, 256, 0, stream>>>(
            x, pp, b2 + lay * DV, lfg, lfb, nullptr, (float*)d_out);
    } else {
      gemm_k<2><<<dim3(16, 8, 1), 512, 0, stream>>>(
          mb, WTL + (size_t)8 * DV * DV, b2 + lay * DV, nullptr, nullptr,
          nullptr, nullptr, nullptr, nullptr, x, x, NTOK, DV, FF, 0);
      if (lay < NLAY - 1)
        ln_k<0><<<NTOK, 256, 0, stream>>>(x, l1g + (lay + 1) * DV,
                                          l1b + (lay + 1) * DV, hb, nullptr);
      else
        ln_k<1><<<NTOK, 256, 0, stream>>>(x, lfg, lfb, nullptr, (float*)d_out);
    }
  }
}

// Round 14
// 859.718 us; speedup vs baseline: 1.0486x; 1.0024x over previous
//
#include <hip/hip_runtime.h>
#include <hip/hip_bf16.h>
#include <math.h>

#define DV 1024
#define FF 4096
#define NLAY 6
#define NH 16
#define TT 1024
#define NTOK 2048

typedef float f32x4 __attribute__((ext_vector_type(4)));
typedef short bf16x8 __attribute__((ext_vector_type(8)));
typedef unsigned short u16;
typedef u16 u16x4 __attribute__((ext_vector_type(4)));
typedef u16 u16x8 __attribute__((ext_vector_type(8)));

__device__ __forceinline__ u16 f2b(float f) {
  unsigned u = __float_as_uint(f);
  unsigned r = (u + 0x7fffu + ((u >> 16) & 1u)) >> 16;  // RNE, finite inputs
  return (u16)r;
}
__device__ __forceinline__ float b2f(u16 u) {
  return __uint_as_float(((unsigned)u) << 16);
}

__device__ __forceinline__ void gload_lds16(const void* g, void* lds) {
  __builtin_amdgcn_global_load_lds(
      (const __attribute__((address_space(1))) void*)g,
      (__attribute__((address_space(3))) void*)lds, 16, 0, 0);
}

// ---------- embed + LN1(layer0) fused ----------
__global__ __launch_bounds__(256) void embed_ln_k(const int* __restrict__ ids,
                                                  const float* __restrict__ wte,
                                                  const float* __restrict__ wpe,
                                                  const float* __restrict__ gg,
                                                  const float* __restrict__ bb,
                                                  float* __restrict__ X,
                                                  u16* __restrict__ outb) {
  int row = blockIdx.x, tid = threadIdx.x;
  int t = row & (TT - 1);
  int id = ids[row];
  f32x4 a = *(const f32x4*)(wte + (size_t)id * DV + tid * 4);
  f32x4 p = *(const f32x4*)(wpe + (size_t)t * DV + tid * 4);
  f32x4 v = a + p;
  *(f32x4*)(X + (size_t)row * DV + tid * 4) = v;
  float s1 = v[0] + v[1] + v[2] + v[3];
  float s2 = v[0] * v[0] + v[1] * v[1] + v[2] * v[2] + v[3] * v[3];
#pragma unroll
  for (int o = 32; o >= 1; o >>= 1) {
    s1 += __shfl_xor(s1, o);
    s2 += __shfl_xor(s2, o);
  }
  __shared__ float sh[8];
  int w = tid >> 6;
  if ((tid & 63) == 0) { sh[w] = s1; sh[w + 4] = s2; }
  __syncthreads();
  s1 = sh[0] + sh[1] + sh[2] + sh[3];
  s2 = sh[4] + sh[5] + sh[6] + sh[7];
  float mean = s1 * (1.0f / DV);
  float var = s2 * (1.0f / DV) - mean * mean;
  float rstd = rsqrtf(var + 1e-5f);
  f32x4 gv = *(const f32x4*)(gg + tid * 4);
  f32x4 bv = *(const f32x4*)(bb + tid * 4);
  u16x4 r;
#pragma unroll
  for (int i = 0; i < 4; ++i) r[i] = f2b((v[i] - mean) * rstd * gv[i] + bv[i]);
  *(u16x4*)(outb + (size_t)row * DV + tid * 4) = r;
}

// ---------- plain LN (fallback path) ----------
template <int OUTF>
__global__ __launch_bounds__(256) void ln_k(const float* __restrict__ X,
                                            const float* __restrict__ gg,
                                            const float* __restrict__ bb,
                                            u16* __restrict__ outb,
                                            float* __restrict__ outf) {
  int row = blockIdx.x, tid = threadIdx.x;
  f32x4 v = *(const f32x4*)(X + (size_t)row * DV + tid * 4);
  float s1 = v[0] + v[1] + v[2] + v[3];
  float s2 = v[0] * v[0] + v[1] * v[1] + v[2] * v[2] + v[3] * v[3];
#pragma unroll
  for (int o = 32; o >= 1; o >>= 1) {
    s1 += __shfl_xor(s1, o);
    s2 += __shfl_xor(s2, o);
  }
  __shared__ float sh[8];
  int w = tid >> 6;
  if ((tid & 63) == 0) { sh[w] = s1; sh[w + 4] = s2; }
  __syncthreads();
  s1 = sh[0] + sh[1] + sh[2] + sh[3];
  s2 = sh[4] + sh[5] + sh[6] + sh[7];
  float mean = s1 * (1.0f / DV);
  float var = s2 * (1.0f / DV) - mean * mean;
  float rstd = rsqrtf(var + 1e-5f);
  f32x4 gv = *(const f32x4*)(gg + tid * 4);
  f32x4 bv = *(const f32x4*)(bb + tid * 4);
  f32x4 o;
#pragma unroll
  for (int i = 0; i < 4; ++i) o[i] = (v[i] - mean) * rstd * gv[i] + bv[i];
  if (OUTF) {
    *(f32x4*)(outf + (size_t)row * DV + tid * 4) = o;
  } else {
    u16x4 r = {f2b(o[0]), f2b(o[1]), f2b(o[2]), f2b(o[3])};
    *(u16x4*)(outb + (size_t)row * DV + tid * 4) = r;
  }
}

// ---------- fused: x += bias + sum(bf16 partials); LN(x) ----------
template <int NS, int OUTF>
__global__ __launch_bounds__(256) void reduce_ln_k(
    float* __restrict__ X, const u16* __restrict__ pp,
    const float* __restrict__ bias, const float* __restrict__ gg,
    const float* __restrict__ bb, u16* __restrict__ outb,
    float* __restrict__ outf) {
  int row = blockIdx.x, tid = threadIdx.x;
  size_t off = (size_t)row * DV + tid * 4;
  f32x4 v = *(const f32x4*)(X + off);
  if (NS > 0) {
    f32x4 bvv = *(const f32x4*)(bias + tid * 4);
    v += bvv;
#pragma unroll
    for (int s = 0; s < NS; ++s) {
      u16x4 pv = *(const u16x4*)(pp + (size_t)s * NTOK * DV + off);
      v[0] += b2f(pv[0]); v[1] += b2f(pv[1]);
      v[2] += b2f(pv[2]); v[3] += b2f(pv[3]);
    }
    *(f32x4*)(X + off) = v;
  }
  float s1 = v[0] + v[1] + v[2] + v[3];
  float s2 = v[0] * v[0] + v[1] * v[1] + v[2] * v[2] + v[3] * v[3];
#pragma unroll
  for (int o = 32; o >= 1; o >>= 1) {
    s1 += __shfl_xor(s1, o);
    s2 += __shfl_xor(s2, o);
  }
  __shared__ float sh[8];
  int w = tid >> 6;
  if ((tid & 63) == 0) { sh[w] = s1; sh[w + 4] = s2; }
  __syncthreads();
  s1 = sh[0] + sh[1] + sh[2] + sh[3];
  s2 = sh[4] + sh[5] + sh[6] + sh[7];
  float mean = s1 * (1.0f / DV);
  float var = s2 * (1.0f / DV) - mean * mean;
  float rstd = rsqrtf(var + 1e-5f);
  f32x4 gv = *(const f32x4*)(gg + tid * 4);
  f32x4 bv = *(const f32x4*)(bb + tid * 4);
  f32x4 o;
#pragma unroll
  for (int i = 0; i < 4; ++i) o[i] = (v[i] - mean) * rstd * gv[i] + bv[i];
  if (OUTF) {
    *(f32x4*)(outf + off) = o;
  } else {
    u16x4 r = {f2b(o[0]), f2b(o[1]), f2b(o[2]), f2b(o[3])};
    *(u16x4*)(outb + off) = r;
  }
}

// ---------- weight transpose: W[K][N] f32 -> WT[N][K] bf16 (retired from tuning) ----------
__global__ __launch_bounds__(256) void transw_k(const float* __restrict__ wq,
                                                const float* __restrict__ wk,
                                                const float* __restrict__ wv,
                                                const float* __restrict__ wo,
                                                const float* __restrict__ w1,
                                                const float* __restrict__ w2,
                                                u16* __restrict__ WT) {
  int lay = blockIdx.y;
  size_t oDD = (size_t)lay * DV * DV, oDF = (size_t)lay * DV * FF;
  u16* WTL = WT + (size_t)lay * 12 * 1024 * 1024;
  int bid = blockIdx.x;
  const float* src;
  u16* dst;
  int K, N, tile;
  if (bid < 256) {
    int which = bid >> 6;
    src = (which == 0 ? wq : which == 1 ? wk : which == 2 ? wv : wo) + oDD;
    dst = WTL + (size_t)which * (DV * DV);
    K = DV; N = DV; tile = bid & 63;
  } else if (bid < 512) {
    src = w1 + oDF; dst = WTL + (size_t)4 * (DV * DV); K = DV; N = FF; tile = bid - 256;
  } else {
    src = w2 + oDF; dst = WTL + (size_t)8 * (DV * DV); K = FF; N = DV; tile = bid - 512;
  }
  int ntc = N >> 8;
  int tr = tile / ntc, tc = tile - tr * ntc;
  int k0 = tr * 64, n0 = tc * 256;
  __shared__ u16 ts[64][258];
  int tid = threadIdx.x, l = tid & 63, w = tid >> 6;
  f32x4 vv[16];
#pragma unroll
  for (int i = 0; i < 16; ++i)
    vv[i] = *(const f32x4*)(src + (size_t)(k0 + i * 4 + w) * N + n0 + l * 4);
#pragma unroll
  for (int i = 0; i < 16; ++i) {
    u16x4 c = {f2b(vv[i][0]), f2b(vv[i][1]), f2b(vv[i][2]), f2b(vv[i][3])};
    *(u16x4*)(&ts[i * 4 + w][l * 4]) = c;
  }
  __syncthreads();
  int kk = (tid & 7) * 8, nn = tid >> 3;
#pragma unroll
  for (int j = 0; j < 8; ++j) {
    int n = j * 32 + nn;
    u16x8 ov;
#pragma unroll
    for (int m = 0; m < 8; ++m) ov[m] = ts[kk + m][n];
    *(u16x8*)(dst + (size_t)(n0 + n) * K + k0 + kk) = ov;
  }
}

// ---------- GEMM 128x128: 512 thr / 8 waves, BK=64 dbuf, T2 swizzle ----------
// (R10 structure — measured best; R4/R5 pipelines and R11 256-tile refuted.)
// EPI 0: bf16 out + bias; z==0 -> o0 SCALED 0.125 (Q); z==1 -> o1; z==2 -> b2v, TRANSPOSED o2t
// EPI 1: bf16 out + bias + exact GELU
// EPI 2: f32 out = res + C + bias (fallback, unstaged)
// EPI 3: bf16 raw partial to op + z*M*N, K range [z*KS,(z+1)*KS)
template <int EPI>
__global__ __launch_bounds__(512) void gemm_k(
    const u16* __restrict__ A, const u16* __restrict__ Wt,
    const float* __restrict__ b0, const float* __restrict__ b1,
    const float* __restrict__ b2v, u16* __restrict__ o0, u16* __restrict__ o1,
    u16* __restrict__ o2t, u16* __restrict__ op, float* __restrict__ of,
    const float* __restrict__ res, int M, int N, int K, int KS) {
  int z = blockIdx.z;
  const u16* W = Wt;
  const float* bias = b0;
  u16* outb = o0;
  if (EPI == 0) {
    W = Wt + (size_t)z * N * K;
    bias = z == 0 ? b0 : z == 1 ? b1 : b2v;
    outb = z == 0 ? o0 : o1;
  }
  int gx = gridDim.x, nwg = gx * gridDim.y;
  int lin = blockIdx.y * gx + blockIdx.x;
  int cpx = nwg >> 3;
  int swz = (lin & 7) * cpx + (lin >> 3);
  int bm = (swz % gx) * 128, bn = (swz / gx) * 128;
  int kbeg = (EPI == 3) ? z * KS : 0;
  int klen = (EPI == 3) ? KS : K;
  __shared__ __attribute__((aligned(16))) u16 SM[32768];  // 64 KB
  u16* As = SM;
  u16* Bs = SM + 16384;
  u16* Cs = SM;
  int tid = threadIdx.x, l = tid & 63, w = tid >> 6;
  int q = l & 15, g = l >> 4;
  int wm = (w >> 1) * 32, wn = (w & 1) * 64;
  int srow = w * 16 + (l >> 3);
  int scol = (((l & 7) ^ ((l >> 3) & 7))) * 8;
  const u16* Ab = A + (size_t)(bm + srow) * K + kbeg + scol;
  const u16* Wb = W + (size_t)(bn + srow) * K + kbeg + scol;
  f32x4 acc[2][4] = {};
  int nk = klen >> 6;
#pragma unroll
  for (int i = 0; i < 2; ++i) {
    gload_lds16(Ab + (size_t)i * 8 * K, &As[(w * 16 + i * 8) * 64]);
    gload_lds16(Wb + (size_t)i * 8 * K, &Bs[(w * 16 + i * 8) * 64]);
  }
  __syncthreads();
  for (int t = 0; t < nk; ++t) {
    int cur = t & 1;
    if (t + 1 < nk) {
      int ko = (t + 1) * 64;
#pragma unroll
      for (int i = 0; i < 2; ++i) {
        gload_lds16(Ab + (size_t)i * 8 * K + ko,
                    &As[(cur ^ 1) * 8192 + (w * 16 + i * 8) * 64]);
        gload_lds16(Wb + (size_t)i * 8 * K + ko,
                    &Bs[(cur ^ 1) * 8192 + (w * 16 + i * 8) * 64]);
      }
    }
#pragma unroll
    for (int kk = 0; kk < 2; ++kk) {
      bf16x8 af[2], bfr[4];
#pragma unroll
      for (int f = 0; f < 2; ++f) {
        int ra = wm + f * 16 + q;
        af[f] = *(const bf16x8*)(&As[cur * 8192 + ra * 64 + ((kk * 4 + g) ^ (ra & 7)) * 8]);
      }
#pragma unroll
      for (int f = 0; f < 4; ++f) {
        int rb = wn + f * 16 + q;
        bfr[f] = *(const bf16x8*)(&Bs[cur * 8192 + rb * 64 + ((kk * 4 + g) ^ (rb & 7)) * 8]);
      }
#pragma unroll
      for (int fm = 0; fm < 2; ++fm)
#pragma unroll
        for (int fn = 0; fn < 4; ++fn)
          acc[fm][fn] = __builtin_amdgcn_mfma_f32_16x16x32_bf16(af[fm], bfr[fn],
                                                                acc[fm][fn], 0, 0, 0);
    }
    __syncthreads();
  }
  if (EPI == 2) {
#pragma unroll
    for (int fm = 0; fm < 2; ++fm)
#pragma unroll
      for (int fn = 0; fn < 4; ++fn) {
        int gcol = bn + wn + fn * 16 + q;
        int growb = bm + wm + fm * 16 + g * 4;
        float bv = bias[gcol];
#pragma unroll
        for (int r = 0; r < 4; ++r)
          of[(size_t)(growb + r) * N + gcol] = res[(size_t)(growb + r) * N + gcol]
                                               + acc[fm][fn][r] + bv;
      }
    return;
  }
  bool tr = (EPI == 0 && z == 2);
#pragma unroll
  for (int fm = 0; fm < 2; ++fm) {
#pragma unroll
    for (int fn = 0; fn < 4; ++fn) {
      int cL = wn + fn * 16 + q;
      float bv = (EPI == 3) ? 0.0f : bias[bn + cL];
#pragma unroll
      for (int r = 0; r < 4; ++r) {
        int rL = wm + fm * 16 + g * 4 + r;
        float v = acc[fm][fn][r] + bv;
        if (EPI == 1) v = 0.5f * v * (1.0f + erff(v * 0.70710678118f));
        if (EPI == 0 && z == 0) v *= 0.125f;
        if (tr) Cs[cL * 132 + rL] = f2b(v);
        else    Cs[rL * 132 + cL] = f2b(v);
      }
    }
  }
  __syncthreads();
  {
    int rowL = tid >> 4, c8 = (tid & 15) * 8;
#pragma unroll
    for (int p = 0; p < 4; ++p) {
      int row = p * 32 + rowL;
      u16x4 lo = *(const u16x4*)(&Cs[row * 132 + c8]);
      u16x4 hi = *(const u16x4*)(&Cs[row * 132 + c8 + 4]);
      u16x8 ov = {lo[0], lo[1], lo[2], lo[3], hi[0], hi[1], hi[2], hi[3]};
      if (tr) {
        *(u16x8*)(o2t + (size_t)(bn + row) * M + bm + c8) = ov;
      } else if (EPI == 3) {
        *(u16x8*)(op + (size_t)z * M * N + (size_t)(bm + row) * N + bn + c8) = ov;
      } else {
        *(u16x8*)(outb + (size_t)(bm + row) * N + bn + c8) = ov;
      }
    }
  }
}

// ---------- flash attention; KVBLK=64, defer-max, Q pre-scaled; V^T input ----------
// XCD-affinity block swizzle; T5 setprio around MFMA clusters.
__global__ __launch_bounds__(256) void attn_k(const u16* __restrict__ Q,
                                              const u16* __restrict__ Kb,
                                              const u16* __restrict__ Vt,
                                              u16* __restrict__ O) {
  int hw = blockIdx.x;                        // 512 blocks, 512 % 8 == 0
  int bid = (hw & 7) * 64 + (hw >> 3);        // bijective; same-XCD hw ids -> same (h,b)
  int qt = bid & 15, h = (bid >> 4) & 15, b = bid >> 8;
  int tid = threadIdx.x, l = tid & 63, w = tid >> 6;
  int q = l & 15, g = l >> 4;
  int tokbase = b * TT;
  int qbase = tokbase + qt * 64 + w * 16;
  __shared__ __attribute__((aligned(16))) u16 Ks[2][64 * 64];
  __shared__ __attribute__((aligned(16))) u16 Vs[2][64 * 64];
  __shared__ __attribute__((aligned(16))) u16 Ps[4][1024];
  bf16x8 qf[2];
  {
    int qrow = qbase + q;
#pragma unroll
    for (int half = 0; half < 2; ++half)
      qf[half] = *(const bf16x8*)(Q + (size_t)qrow * DV + h * 64 + half * 32 + g * 8);
  }
  int rr = tid >> 3, cc = tid & 7;
  const u16* ksrc = Kb + (size_t)(tokbase + rr) * DV + h * 64 + ((cc ^ (rr & 7)) * 8);
  const u16* vsrc = Vt + (size_t)(h * 64 + rr) * NTOK + tokbase + ((cc ^ (rr & 7)) * 8);
  const size_t kst = (size_t)32 * DV;
  const size_t vst = (size_t)32 * NTOK;
  f32x4 oacc[4] = {};
  float m_run = -INFINITY, l_run = 0.0f;
#define AST(bb_, t)                                                      \
  {                                                                      \
    gload_lds16(ksrc + (size_t)(t) * 64 * DV, &Ks[bb_][tid * 8]);        \
    gload_lds16(ksrc + (size_t)(t) * 64 * DV + kst, &Ks[bb_][2048 + tid * 8]); \
    gload_lds16(vsrc + (t) * 64, &Vs[bb_][tid * 8]);                     \
    gload_lds16(vsrc + (t) * 64 + vst, &Vs[bb_][2048 + tid * 8]);        \
  }
  AST(0, 0);
  __syncthreads();
  const int nkb = TT / 64;
  for (int kbk = 0; kbk < nkb; ++kbk) {
    int cur = kbk & 1;
    if (kbk + 1 < nkb) AST(cur ^ 1, kbk + 1);
    f32x4 s[4] = {};
    __builtin_amdgcn_s_setprio(1);
#pragma unroll
    for (int kt = 0; kt < 4; ++kt) {
      int row = kt * 16 + q;
#pragma unroll
      for (int half = 0; half < 2; ++half) {
        int chunk = (half * 4 + g) ^ (row & 7);
        bf16x8 kf = *(const bf16x8*)(&Ks[cur][row * 64 + chunk * 8]);
        s[kt] = __builtin_amdgcn_mfma_f32_16x16x32_bf16(kf, qf[half], s[kt], 0, 0, 0);
      }
    }
    __builtin_amdgcn_s_setprio(0);
    float tmax = -INFINITY;
#pragma unroll
    for (int kt = 0; kt < 4; ++kt)
#pragma unroll
      for (int r = 0; r < 4; ++r) tmax = fmaxf(tmax, s[kt][r]);
    tmax = fmaxf(tmax, __shfl_xor(tmax, 16));
    tmax = fmaxf(tmax, __shfl_xor(tmax, 32));
    if (!__all(tmax <= m_run + 8.0f)) {
      float m_new = fmaxf(m_run, tmax);
      float corr = __expf(m_run - m_new);
      float corr4[4];
#pragma unroll
      for (int r = 0; r < 4; ++r) corr4[r] = __shfl(corr, g * 4 + r);
#pragma unroll
      for (int nt = 0; nt < 4; ++nt)
#pragma unroll
        for (int r = 0; r < 4; ++r) oacc[nt][r] *= corr4[r];
      l_run *= corr;
      m_run = m_new;
    }
    float psum = 0.0f;
    u16x4 pb[4];
#pragma unroll
    for (int kt = 0; kt < 4; ++kt)
#pragma unroll
      for (int r = 0; r < 4; ++r) {
        float p = __expf(s[kt][r] - m_run);
        psum += p;
        pb[kt][r] = f2b(p);
      }
    psum += __shfl_xor(psum, 16);
    psum += __shfl_xor(psum, 32);
    l_run += psum;
#pragma unroll
    for (int kt = 0; kt < 4; ++kt)
      *(u16x4*)(&Ps[w][q * 64 + ((kt * 4 + g) ^ (q & 7)) * 4]) = pb[kt];
    __builtin_amdgcn_s_setprio(1);
#pragma unroll
    for (int kt2 = 0; kt2 < 2; ++kt2) {
      int c0 = kt2 * 8 + (g >> 1) * 4 + (g & 1) * 2;
      u16x4 a0 = *(const u16x4*)(&Ps[w][q * 64 + ((c0) ^ (q & 7)) * 4]);
      u16x4 a1 = *(const u16x4*)(&Ps[w][q * 64 + ((c0 + 1) ^ (q & 7)) * 4]);
      bf16x8 pa = {(short)a0[0], (short)a0[1], (short)a0[2], (short)a0[3],
                   (short)a1[0], (short)a1[1], (short)a1[2], (short)a1[3]};
#pragma unroll
      for (int nt = 0; nt < 4; ++nt) {
        int vrow = nt * 16 + q;
        int vc = (kt2 * 4 + g) ^ (vrow & 7);
        bf16x8 vf = *(const bf16x8*)(&Vs[cur][vrow * 64 + vc * 8]);
        oacc[nt] = __builtin_amdgcn_mfma_f32_16x16x32_bf16(pa, vf, oacc[nt], 0, 0, 0);
      }
    }
    __builtin_amdgcn_s_setprio(0);
    __syncthreads();
  }
#undef AST
  float rl[4];
#pragma unroll
  for (int r = 0; r < 4; ++r) rl[r] = 1.0f / __shfl(l_run, g * 4 + r);
#pragma unroll
  for (int nt = 0; nt < 4; ++nt)
#pragma unroll
    for (int r = 0; r < 4; ++r) {
      int qrw = qbase + g * 4 + r;
      int d = nt * 16 + q;
      O[(size_t)qrw * DV + h * 64 + d] = f2b(oacc[nt][r] * rl[r]);
    }
}

extern "C" void kernel_launch(void* const* d_in, const int* in_sizes, int n_in,
                              void* d_out, int out_size, void* d_ws, size_t ws_size,
                              hipStream_t stream) {
  const int*   ids = (const int*)d_in[0];
  const float* wte = (const float*)d_in[1];
  const float* wpe = (const float*)d_in[2];
  const float* l1g = (const float*)d_in[3];
  const float* l1b = (const float*)d_in[4];
  const float* wq  = (const float*)d_in[5];
  const float* bq  = (const float*)d_in[6];
  const float* wk  = (const float*)d_in[7];
  const float* bk  = (const float*)d_in[8];
  const float* wv  = (const float*)d_in[9];
  const float* bv  = (const float*)d_in[10];
  const float* wo  = (const float*)d_in[11];
  const float* bo  = (const float*)d_in[12];
  const float* l2g = (const float*)d_in[13];
  const float* l2b = (const float*)d_in[14];
  const float* w1  = (const float*)d_in[15];
  const float* b1  = (const float*)d_in[16];
  const float* w2  = (const float*)d_in[17];
  const float* b2  = (const float*)d_in[18];
  const float* lfg = (const float*)d_in[19];
  const float* lfb = (const float*)d_in[20];
  (void)in_sizes; (void)n_in; (void)out_size;

  bool bigws = ws_size >= ((size_t)221 << 20);
  bool midws = ws_size >= ((size_t)101 << 20);

  char* ws = (char*)d_ws;
  float* x   = (float*)(ws + 0);                 // 8 MB residual (f32)
  u16*   hb  = (u16*)(ws + ((size_t)8 << 20));   // 4 MB LN out
  u16*   qb  = (u16*)(ws + ((size_t)12 << 20));  // 4 MB (pre-scaled 0.125)
  u16*   kb  = (u16*)(ws + ((size_t)16 << 20));  // 4 MB
  u16*   vbt = (u16*)(ws + ((size_t)20 << 20));  // 4 MB V^T [D][tok]
  u16*   ab  = (u16*)(ws + ((size_t)24 << 20));  // 4 MB attn out
  u16*   mb  = (u16*)(ws + ((size_t)28 << 20));  // 16 MB gelu out
  u16*   pp  = (u16*)(ws + ((size_t)44 << 20));  // 16 MB bf16 partials
  u16*   WT  = (u16*)(ws + ((size_t)(midws ? 76 : 44) << 20));

  if (bigws)
    transw_k<<<dim3(768, 6), 256, 0, stream>>>(wq, wk, wv, wo, w1, w2, WT);
  embed_ln_k<<<NTOK, 256, 0, stream>>>(ids, wte, wpe, l1g, l1b, x, hb);

  for (int lay = 0; lay < NLAY; ++lay) {
    size_t oDD = (size_t)lay * DV * DV;
    size_t oDF = (size_t)lay * DV * FF;
    u16* WTL = bigws ? WT + (size_t)lay * 12 * 1024 * 1024 : WT;
    if (!bigws)
      transw_k<<<dim3(768, 1), 256, 0, stream>>>(wq + oDD, wk + oDD, wv + oDD,
                                                 wo + oDD, w1 + oDF, w2 + oDF, WTL);
    gemm_k<0><<<dim3(16, 8, 3), 512, 0, stream>>>(
        hb, WTL, bq + lay * DV, bk + lay * DV, bv + lay * DV,
        qb, kb, vbt, nullptr, nullptr, nullptr, NTOK, DV, DV, 0);
    attn_k<<<512, 256, 0, stream>>>(qb, kb, vbt, ab);
    if (midws) {
      gemm_k<3><<<dim3(16, 8, 4), 512, 0, stream>>>(
          ab, WTL + (size_t)3 * DV * DV, nullptr, nullptr, nullptr,
          nullptr, nullptr, nullptr, pp, nullptr, nullptr, NTOK, DV, DV, 256);
      reduce_ln_k<4, 0><<<NTOK, 256, 0, stream>>>(
          x, pp, bo + lay * DV, l2g + lay * DV, l2b + lay * DV, hb, nullptr);
    } else {
      gemm_k<2><<<dim3(16, 8, 1), 512, 0, stream>>>(
          ab, WTL + (size_t)3 * DV * DV, bo + lay * DV, nullptr, nullptr,
          nullptr, nullptr, nullptr, nullptr, x, x, NTOK, DV, DV, 0);
      ln_k<0><<<NTOK, 256, 0, stream>>>(x, l2g + lay * DV, l2b + lay * DV, hb, nullptr);
    }
    gemm_k<1><<<dim3(16, 32, 1), 512, 0, stream>>>(
        hb, WTL + (size_t)4 * DV * DV, b1 + lay * FF, nullptr, nullptr,
        mb, nullptr, nullptr, nullptr, nullptr, nullptr, NTOK, FF, DV, 0);
    if (midws) {
      gemm_k<3><<<dim3(16, 8, 4), 512, 0, stream>>>(
          mb, WTL + (size_t)8 * DV * DV, nullptr, nullptr, nullptr,
          nullptr, nullptr, nullptr, pp, nullptr, nullptr, NTOK, DV, FF, 1024);
      if (lay < NLAY - 1)
        reduce_ln_k<4, 0><<<NTOK, 256, 0, stream>>>(
            x, pp, b2 + lay * DV, l1g + (lay + 1) * DV, l1b + (lay + 1) * DV,
            hb, nullptr);
      else
        reduce_ln_k<4, 1><<<NTOK, 256, 0, stream>>>(
            x, pp, b2 + lay * DV, lfg, lfb, nullptr, (float*)d_out);
    } else {
      gemm_k<2><<<dim3(16, 8, 1), 512, 0, stream>>>(
          mb, WTL + (size_t)8 * DV * DV, b2 + lay * DV, nullptr, nullptr,
          nullptr, nullptr, nullptr, nullptr, x, x, NTOK, DV, FF, 0);
      if (lay < NLAY - 1)
        ln_k<0><<<NTOK, 256, 0, stream>>>(x, l1g + (lay + 1) * DV,
                                          l1b + (lay + 1) * DV, hb, nullptr);
      else
        ln_k<1><<<NTOK, 256, 0, stream>>>(x, lfg, lfb, nullptr, (float*)d_out);
    }
  }
}

// Round 15
// 855.595 us; speedup vs baseline: 1.0536x; 1.0048x over previous
//
#include <hip/hip_runtime.h>
#include <hip/hip_bf16.h>
#include <math.h>

#define DV 1024
#define FF 4096
#define NLAY 6
#define NH 16
#define TT 1024
#define NTOK 2048

typedef float f32x4 __attribute__((ext_vector_type(4)));
typedef short bf16x8 __attribute__((ext_vector_type(8)));
typedef unsigned short u16;
typedef u16 u16x4 __attribute__((ext_vector_type(4)));
typedef u16 u16x8 __attribute__((ext_vector_type(8)));

__device__ __forceinline__ u16 f2b(float f) {
  unsigned u = __float_as_uint(f);
  unsigned r = (u + 0x7fffu + ((u >> 16) & 1u)) >> 16;  // RNE, finite inputs
  return (u16)r;
}
__device__ __forceinline__ float b2f(u16 u) {
  return __uint_as_float(((unsigned)u) << 16);
}

__device__ __forceinline__ void gload_lds16(const void* g, void* lds) {
  __builtin_amdgcn_global_load_lds(
      (const __attribute__((address_space(1))) void*)g,
      (__attribute__((address_space(3))) void*)lds, 16, 0, 0);
}

// ---------- embed + LN1(layer0) fused ----------
__global__ __launch_bounds__(256) void embed_ln_k(const int* __restrict__ ids,
                                                  const float* __restrict__ wte,
                                                  const float* __restrict__ wpe,
                                                  const float* __restrict__ gg,
                                                  const float* __restrict__ bb,
                                                  float* __restrict__ X,
                                                  u16* __restrict__ outb) {
  int row = blockIdx.x, tid = threadIdx.x;
  int t = row & (TT - 1);
  int id = ids[row];
  f32x4 a = *(const f32x4*)(wte + (size_t)id * DV + tid * 4);
  f32x4 p = *(const f32x4*)(wpe + (size_t)t * DV + tid * 4);
  f32x4 v = a + p;
  *(f32x4*)(X + (size_t)row * DV + tid * 4) = v;
  float s1 = v[0] + v[1] + v[2] + v[3];
  float s2 = v[0] * v[0] + v[1] * v[1] + v[2] * v[2] + v[3] * v[3];
#pragma unroll
  for (int o = 32; o >= 1; o >>= 1) {
    s1 += __shfl_xor(s1, o);
    s2 += __shfl_xor(s2, o);
  }
  __shared__ float sh[8];
  int w = tid >> 6;
  if ((tid & 63) == 0) { sh[w] = s1; sh[w + 4] = s2; }
  __syncthreads();
  s1 = sh[0] + sh[1] + sh[2] + sh[3];
  s2 = sh[4] + sh[5] + sh[6] + sh[7];
  float mean = s1 * (1.0f / DV);
  float var = s2 * (1.0f / DV) - mean * mean;
  float rstd = rsqrtf(var + 1e-5f);
  f32x4 gv = *(const f32x4*)(gg + tid * 4);
  f32x4 bv = *(const f32x4*)(bb + tid * 4);
  u16x4 r;
#pragma unroll
  for (int i = 0; i < 4; ++i) r[i] = f2b((v[i] - mean) * rstd * gv[i] + bv[i]);
  *(u16x4*)(outb + (size_t)row * DV + tid * 4) = r;
}

// ---------- plain LN (fallback path) ----------
template <int OUTF>
__global__ __launch_bounds__(256) void ln_k(const float* __restrict__ X,
                                            const float* __restrict__ gg,
                                            const float* __restrict__ bb,
                                            u16* __restrict__ outb,
                                            float* __restrict__ outf) {
  int row = blockIdx.x, tid = threadIdx.x;
  f32x4 v = *(const f32x4*)(X + (size_t)row * DV + tid * 4);
  float s1 = v[0] + v[1] + v[2] + v[3];
  float s2 = v[0] * v[0] + v[1] * v[1] + v[2] * v[2] + v[3] * v[3];
#pragma unroll
  for (int o = 32; o >= 1; o >>= 1) {
    s1 += __shfl_xor(s1, o);
    s2 += __shfl_xor(s2, o);
  }
  __shared__ float sh[8];
  int w = tid >> 6;
  if ((tid & 63) == 0) { sh[w] = s1; sh[w + 4] = s2; }
  __syncthreads();
  s1 = sh[0] + sh[1] + sh[2] + sh[3];
  s2 = sh[4] + sh[5] + sh[6] + sh[7];
  float mean = s1 * (1.0f / DV);
  float var = s2 * (1.0f / DV) - mean * mean;
  float rstd = rsqrtf(var + 1e-5f);
  f32x4 gv = *(const f32x4*)(gg + tid * 4);
  f32x4 bv = *(const f32x4*)(bb + tid * 4);
  f32x4 o;
#pragma unroll
  for (int i = 0; i < 4; ++i) o[i] = (v[i] - mean) * rstd * gv[i] + bv[i];
  if (OUTF) {
    *(f32x4*)(outf + (size_t)row * DV + tid * 4) = o;
  } else {
    u16x4 r = {f2b(o[0]), f2b(o[1]), f2b(o[2]), f2b(o[3])};
    *(u16x4*)(outb + (size_t)row * DV + tid * 4) = r;
  }
}

// ---------- fused: x += bias + sum(bf16 partials); LN(x) ----------
template <int NS, int OUTF>
__global__ __launch_bounds__(256) void reduce_ln_k(
    float* __restrict__ X, const u16* __restrict__ pp,
    const float* __restrict__ bias, const float* __restrict__ gg,
    const float* __restrict__ bb, u16* __restrict__ outb,
    float* __restrict__ outf) {
  int row = blockIdx.x, tid = threadIdx.x;
  size_t off = (size_t)row * DV + tid * 4;
  f32x4 v = *(const f32x4*)(X + off);
  if (NS > 0) {
    f32x4 bvv = *(const f32x4*)(bias + tid * 4);
    v += bvv;
#pragma unroll
    for (int s = 0; s < NS; ++s) {
      u16x4 pv = *(const u16x4*)(pp + (size_t)s * NTOK * DV + off);
      v[0] += b2f(pv[0]); v[1] += b2f(pv[1]);
      v[2] += b2f(pv[2]); v[3] += b2f(pv[3]);
    }
    *(f32x4*)(X + off) = v;
  }
  float s1 = v[0] + v[1] + v[2] + v[3];
  float s2 = v[0] * v[0] + v[1] * v[1] + v[2] * v[2] + v[3] * v[3];
#pragma unroll
  for (int o = 32; o >= 1; o >>= 1) {
    s1 += __shfl_xor(s1, o);
    s2 += __shfl_xor(s2, o);
  }
  __shared__ float sh[8];
  int w = tid >> 6;
  if ((tid & 63) == 0) { sh[w] = s1; sh[w + 4] = s2; }
  __syncthreads();
  s1 = sh[0] + sh[1] + sh[2] + sh[3];
  s2 = sh[4] + sh[5] + sh[6] + sh[7];
  float mean = s1 * (1.0f / DV);
  float var = s2 * (1.0f / DV) - mean * mean;
  float rstd = rsqrtf(var + 1e-5f);
  f32x4 gv = *(const f32x4*)(gg + tid * 4);
  f32x4 bv = *(const f32x4*)(bb + tid * 4);
  f32x4 o;
#pragma unroll
  for (int i = 0; i < 4; ++i) o[i] = (v[i] - mean) * rstd * gv[i] + bv[i];
  if (OUTF) {
    *(f32x4*)(outf + off) = o;
  } else {
    u16x4 r = {f2b(o[0]), f2b(o[1]), f2b(o[2]), f2b(o[3])};
    *(u16x4*)(outb + off) = r;
  }
}

// ---------- weight transpose: W[K][N] f32 -> WT[N][K] bf16 ----------
// R14: nontemporal loads+stores (touch-once data; bypass cache allocation to
// test the mixed-stream / cache-pollution hypothesis for the 2.5 TB/s plateau).
__global__ __launch_bounds__(256) void transw_k(const float* __restrict__ wq,
                                                const float* __restrict__ wk,
                                                const float* __restrict__ wv,
                                                const float* __restrict__ wo,
                                                const float* __restrict__ w1,
                                                const float* __restrict__ w2,
                                                u16* __restrict__ WT) {
  int lay = blockIdx.y;
  size_t oDD = (size_t)lay * DV * DV, oDF = (size_t)lay * DV * FF;
  u16* WTL = WT + (size_t)lay * 12 * 1024 * 1024;
  int bid = blockIdx.x;
  const float* src;
  u16* dst;
  int K, N, tile;
  if (bid < 256) {
    int which = bid >> 6;
    src = (which == 0 ? wq : which == 1 ? wk : which == 2 ? wv : wo) + oDD;
    dst = WTL + (size_t)which * (DV * DV);
    K = DV; N = DV; tile = bid & 63;
  } else if (bid < 512) {
    src = w1 + oDF; dst = WTL + (size_t)4 * (DV * DV); K = DV; N = FF; tile = bid - 256;
  } else {
    src = w2 + oDF; dst = WTL + (size_t)8 * (DV * DV); K = FF; N = DV; tile = bid - 512;
  }
  int ntc = N >> 8;
  int tr = tile / ntc, tc = tile - tr * ntc;
  int k0 = tr * 64, n0 = tc * 256;
  __shared__ u16 ts[64][258];
  int tid = threadIdx.x, l = tid & 63, w = tid >> 6;
  f32x4 vv[16];
#pragma unroll
  for (int i = 0; i < 16; ++i)
    vv[i] = __builtin_nontemporal_load(
        (const f32x4*)(src + (size_t)(k0 + i * 4 + w) * N + n0 + l * 4));
#pragma unroll
  for (int i = 0; i < 16; ++i) {
    u16x4 c = {f2b(vv[i][0]), f2b(vv[i][1]), f2b(vv[i][2]), f2b(vv[i][3])};
    *(u16x4*)(&ts[i * 4 + w][l * 4]) = c;
  }
  __syncthreads();
  int kk = (tid & 7) * 8, nn = tid >> 3;
#pragma unroll
  for (int j = 0; j < 8; ++j) {
    int n = j * 32 + nn;
    u16x8 ov;
#pragma unroll
    for (int m = 0; m < 8; ++m) ov[m] = ts[kk + m][n];
    __builtin_nontemporal_store(ov, (u16x8*)(dst + (size_t)(n0 + n) * K + k0 + kk));
  }
}

// ---------- GEMM 128x128: 512 thr / 8 waves, BK=64 dbuf, T2 swizzle ----------
// (R10 structure — measured best; R4/R5 pipelines and R11 256-tile refuted.)
// EPI 0: bf16 out + bias; z==0 -> o0 SCALED 0.125 (Q); z==1 -> o1; z==2 -> b2v, TRANSPOSED o2t
// EPI 1: bf16 out + bias + exact GELU
// EPI 2: f32 out = res + C + bias (fallback, unstaged)
// EPI 3: bf16 raw partial to op + z*M*N, K range [z*KS,(z+1)*KS)
template <int EPI>
__global__ __launch_bounds__(512) void gemm_k(
    const u16* __restrict__ A, const u16* __restrict__ Wt,
    const float* __restrict__ b0, const float* __restrict__ b1,
    const float* __restrict__ b2v, u16* __restrict__ o0, u16* __restrict__ o1,
    u16* __restrict__ o2t, u16* __restrict__ op, float* __restrict__ of,
    const float* __restrict__ res, int M, int N, int K, int KS) {
  int z = blockIdx.z;
  const u16* W = Wt;
  const float* bias = b0;
  u16* outb = o0;
  if (EPI == 0) {
    W = Wt + (size_t)z * N * K;
    bias = z == 0 ? b0 : z == 1 ? b1 : b2v;
    outb = z == 0 ? o0 : o1;
  }
  int gx = gridDim.x, nwg = gx * gridDim.y;
  int lin = blockIdx.y * gx + blockIdx.x;
  int cpx = nwg >> 3;
  int swz = (lin & 7) * cpx + (lin >> 3);
  int bm = (swz % gx) * 128, bn = (swz / gx) * 128;
  int kbeg = (EPI == 3) ? z * KS : 0;
  int klen = (EPI == 3) ? KS : K;
  __shared__ __attribute__((aligned(16))) u16 SM[32768];  // 64 KB
  u16* As = SM;
  u16* Bs = SM + 16384;
  u16* Cs = SM;
  int tid = threadIdx.x, l = tid & 63, w = tid >> 6;
  int q = l & 15, g = l >> 4;
  int wm = (w >> 1) * 32, wn = (w & 1) * 64;
  int srow = w * 16 + (l >> 3);
  int scol = (((l & 7) ^ ((l >> 3) & 7))) * 8;
  const u16* Ab = A + (size_t)(bm + srow) * K + kbeg + scol;
  const u16* Wb = W + (size_t)(bn + srow) * K + kbeg + scol;
  f32x4 acc[2][4] = {};
  int nk = klen >> 6;
#pragma unroll
  for (int i = 0; i < 2; ++i) {
    gload_lds16(Ab + (size_t)i * 8 * K, &As[(w * 16 + i * 8) * 64]);
    gload_lds16(Wb + (size_t)i * 8 * K, &Bs[(w * 16 + i * 8) * 64]);
  }
  __syncthreads();
  for (int t = 0; t < nk; ++t) {
    int cur = t & 1;
    if (t + 1 < nk) {
      int ko = (t + 1) * 64;
#pragma unroll
      for (int i = 0; i < 2; ++i) {
        gload_lds16(Ab + (size_t)i * 8 * K + ko,
                    &As[(cur ^ 1) * 8192 + (w * 16 + i * 8) * 64]);
        gload_lds16(Wb + (size_t)i * 8 * K + ko,
                    &Bs[(cur ^ 1) * 8192 + (w * 16 + i * 8) * 64]);
      }
    }
#pragma unroll
    for (int kk = 0; kk < 2; ++kk) {
      bf16x8 af[2], bfr[4];
#pragma unroll
      for (int f = 0; f < 2; ++f) {
        int ra = wm + f * 16 + q;
        af[f] = *(const bf16x8*)(&As[cur * 8192 + ra * 64 + ((kk * 4 + g) ^ (ra & 7)) * 8]);
      }
#pragma unroll
      for (int f = 0; f < 4; ++f) {
        int rb = wn + f * 16 + q;
        bfr[f] = *(const bf16x8*)(&Bs[cur * 8192 + rb * 64 + ((kk * 4 + g) ^ (rb & 7)) * 8]);
      }
#pragma unroll
      for (int fm = 0; fm < 2; ++fm)
#pragma unroll
        for (int fn = 0; fn < 4; ++fn)
          acc[fm][fn] = __builtin_amdgcn_mfma_f32_16x16x32_bf16(af[fm], bfr[fn],
                                                                acc[fm][fn], 0, 0, 0);
    }
    __syncthreads();
  }
  if (EPI == 2) {
#pragma unroll
    for (int fm = 0; fm < 2; ++fm)
#pragma unroll
      for (int fn = 0; fn < 4; ++fn) {
        int gcol = bn + wn + fn * 16 + q;
        int growb = bm + wm + fm * 16 + g * 4;
        float bv = bias[gcol];
#pragma unroll
        for (int r = 0; r < 4; ++r)
          of[(size_t)(growb + r) * N + gcol] = res[(size_t)(growb + r) * N + gcol]
                                               + acc[fm][fn][r] + bv;
      }
    return;
  }
  bool tr = (EPI == 0 && z == 2);
#pragma unroll
  for (int fm = 0; fm < 2; ++fm) {
#pragma unroll
    for (int fn = 0; fn < 4; ++fn) {
      int cL = wn + fn * 16 + q;
      float bv = (EPI == 3) ? 0.0f : bias[bn + cL];
#pragma unroll
      for (int r = 0; r < 4; ++r) {
        int rL = wm + fm * 16 + g * 4 + r;
        float v = acc[fm][fn][r] + bv;
        if (EPI == 1) v = 0.5f * v * (1.0f + erff(v * 0.70710678118f));
        if (EPI == 0 && z == 0) v *= 0.125f;
        if (tr) Cs[cL * 132 + rL] = f2b(v);
        else    Cs[rL * 132 + cL] = f2b(v);
      }
    }
  }
  __syncthreads();
  {
    int rowL = tid >> 4, c8 = (tid & 15) * 8;
#pragma unroll
    for (int p = 0; p < 4; ++p) {
      int row = p * 32 + rowL;
      u16x4 lo = *(const u16x4*)(&Cs[row * 132 + c8]);
      u16x4 hi = *(const u16x4*)(&Cs[row * 132 + c8 + 4]);
      u16x8 ov = {lo[0], lo[1], lo[2], lo[3], hi[0], hi[1], hi[2], hi[3]};
      if (tr) {
        *(u16x8*)(o2t + (size_t)(bn + row) * M + bm + c8) = ov;
      } else if (EPI == 3) {
        *(u16x8*)(op + (size_t)z * M * N + (size_t)(bm + row) * N + bn + c8) = ov;
      } else {
        *(u16x8*)(outb + (size_t)(bm + row) * N + bn + c8) = ov;
      }
    }
  }
}

// ---------- flash attention; KVBLK=64, defer-max, Q pre-scaled; V^T input ----------
// XCD-affinity block swizzle; T5 setprio around MFMA clusters.
__global__ __launch_bounds__(256) void attn_k(const u16* __restrict__ Q,
                                              const u16* __restrict__ Kb,
                                              const u16* __restrict__ Vt,
                                              u16* __restrict__ O) {
  int hw = blockIdx.x;                        // 512 blocks, 512 % 8 == 0
  int bid = (hw & 7) * 64 + (hw >> 3);        // bijective; same-XCD hw ids -> same (h,b)
  int qt = bid & 15, h = (bid >> 4) & 15, b = bid >> 8;
  int tid = threadIdx.x, l = tid & 63, w = tid >> 6;
  int q = l & 15, g = l >> 4;
  int tokbase = b * TT;
  int qbase = tokbase + qt * 64 + w * 16;
  __shared__ __attribute__((aligned(16))) u16 Ks[2][64 * 64];
  __shared__ __attribute__((aligned(16))) u16 Vs[2][64 * 64];
  __shared__ __attribute__((aligned(16))) u16 Ps[4][1024];
  bf16x8 qf[2];
  {
    int qrow = qbase + q;
#pragma unroll
    for (int half = 0; half < 2; ++half)
      qf[half] = *(const bf16x8*)(Q + (size_t)qrow * DV + h * 64 + half * 32 + g * 8);
  }
  int rr = tid >> 3, cc = tid & 7;
  const u16* ksrc = Kb + (size_t)(tokbase + rr) * DV + h * 64 + ((cc ^ (rr & 7)) * 8);
  const u16* vsrc = Vt + (size_t)(h * 64 + rr) * NTOK + tokbase + ((cc ^ (rr & 7)) * 8);
  const size_t kst = (size_t)32 * DV;
  const size_t vst = (size_t)32 * NTOK;
  f32x4 oacc[4] = {};
  float m_run = -INFINITY, l_run = 0.0f;
#define AST(bb_, t)                                                      \
  {                                                                      \
    gload_lds16(ksrc + (size_t)(t) * 64 * DV, &Ks[bb_][tid * 8]);        \
    gload_lds16(ksrc + (size_t)(t) * 64 * DV + kst, &Ks[bb_][2048 + tid * 8]); \
    gload_lds16(vsrc + (t) * 64, &Vs[bb_][tid * 8]);                     \
    gload_lds16(vsrc + (t) * 64 + vst, &Vs[bb_][2048 + tid * 8]);        \
  }
  AST(0, 0);
  __syncthreads();
  const int nkb = TT / 64;
  for (int kbk = 0; kbk < nkb; ++kbk) {
    int cur = kbk & 1;
    if (kbk + 1 < nkb) AST(cur ^ 1, kbk + 1);
    f32x4 s[4] = {};
    __builtin_amdgcn_s_setprio(1);
#pragma unroll
    for (int kt = 0; kt < 4; ++kt) {
      int row = kt * 16 + q;
#pragma unroll
      for (int half = 0; half < 2; ++half) {
        int chunk = (half * 4 + g) ^ (row & 7);
        bf16x8 kf = *(const bf16x8*)(&Ks[cur][row * 64 + chunk * 8]);
        s[kt] = __builtin_amdgcn_mfma_f32_16x16x32_bf16(kf, qf[half], s[kt], 0, 0, 0);
      }
    }
    __builtin_amdgcn_s_setprio(0);
    float tmax = -INFINITY;
#pragma unroll
    for (int kt = 0; kt < 4; ++kt)
#pragma unroll
      for (int r = 0; r < 4; ++r) tmax = fmaxf(tmax, s[kt][r]);
    tmax = fmaxf(tmax, __shfl_xor(tmax, 16));
    tmax = fmaxf(tmax, __shfl_xor(tmax, 32));
    if (!__all(tmax <= m_run + 8.0f)) {
      float m_new = fmaxf(m_run, tmax);
      float corr = __expf(m_run - m_new);
      float corr4[4];
#pragma unroll
      for (int r = 0; r < 4; ++r) corr4[r] = __shfl(corr, g * 4 + r);
#pragma unroll
      for (int nt = 0; nt < 4; ++nt)
#pragma unroll
        for (int r = 0; r < 4; ++r) oacc[nt][r] *= corr4[r];
      l_run *= corr;
      m_run = m_new;
    }
    float psum = 0.0f;
    u16x4 pb[4];
#pragma unroll
    for (int kt = 0; kt < 4; ++kt)
#pragma unroll
      for (int r = 0; r < 4; ++r) {
        float p = __expf(s[kt][r] - m_run);
        psum += p;
        pb[kt][r] = f2b(p);
      }
    psum += __shfl_xor(psum, 16);
    psum += __shfl_xor(psum, 32);
    l_run += psum;
#pragma unroll
    for (int kt = 0; kt < 4; ++kt)
      *(u16x4*)(&Ps[w][q * 64 + ((kt * 4 + g) ^ (q & 7)) * 4]) = pb[kt];
    __builtin_amdgcn_s_setprio(1);
#pragma unroll
    for (int kt2 = 0; kt2 < 2; ++kt2) {
      int c0 = kt2 * 8 + (g >> 1) * 4 + (g & 1) * 2;
      u16x4 a0 = *(const u16x4*)(&Ps[w][q * 64 + ((c0) ^ (q & 7)) * 4]);
      u16x4 a1 = *(const u16x4*)(&Ps[w][q * 64 + ((c0 + 1) ^ (q & 7)) * 4]);
      bf16x8 pa = {(short)a0[0], (short)a0[1], (short)a0[2], (short)a0[3],
                   (short)a1[0], (short)a1[1], (short)a1[2], (short)a1[3]};
#pragma unroll
      for (int nt = 0; nt < 4; ++nt) {
        int vrow = nt * 16 + q;
        int vc = (kt2 * 4 + g) ^ (vrow & 7);
        bf16x8 vf = *(const bf16x8*)(&Vs[cur][vrow * 64 + vc * 8]);
        oacc[nt] = __builtin_amdgcn_mfma_f32_16x16x32_bf16(pa, vf, oacc[nt], 0, 0, 0);
      }
    }
    __builtin_amdgcn_s_setprio(0);
    __syncthreads();
  }
#undef AST
  float rl[4];
#pragma unroll
  for (int r = 0; r < 4; ++r) rl[r] = 1.0f / __shfl(l_run, g * 4 + r);
#pragma unroll
  for (int nt = 0; nt < 4; ++nt)
#pragma unroll
    for (int r = 0; r < 4; ++r) {
      int qrw = qbase + g * 4 + r;
      int d = nt * 16 + q;
      O[(size_t)qrw * DV + h * 64 + d] = f2b(oacc[nt][r] * rl[r]);
    }
}

extern "C" void kernel_launch(void* const* d_in, const int* in_sizes, int n_in,
                              void* d_out, int out_size, void* d_ws, size_t ws_size,
                              hipStream_t stream) {
  const int*   ids = (const int*)d_in[0];
  const float* wte = (const float*)d_in[1];
  const float* wpe = (const float*)d_in[2];
  const float* l1g = (const float*)d_in[3];
  const float* l1b = (const float*)d_in[4];
  const float* wq  = (const float*)d_in[5];
  const float* bq  = (const float*)d_in[6];
  const float* wk  = (const float*)d_in[7];
  const float* bk  = (const float*)d_in[8];
  const float* wv  = (const float*)d_in[9];
  const float* bv  = (const float*)d_in[10];
  const float* wo  = (const float*)d_in[11];
  const float* bo  = (const float*)d_in[12];
  const float* l2g = (const float*)d_in[13];
  const float* l2b = (const float*)d_in[14];
  const float* w1  = (const float*)d_in[15];
  const float* b1  = (const float*)d_in[16];
  const float* w2  = (const float*)d_in[17];
  const float* b2  = (const float*)d_in[18];
  const float* lfg = (const float*)d_in[19];
  const float* lfb = (const float*)d_in[20];
  (void)in_sizes; (void)n_in; (void)out_size;

  bool bigws = ws_size >= ((size_t)221 << 20);
  bool midws = ws_size >= ((size_t)101 << 20);

  char* ws = (char*)d_ws;
  float* x   = (float*)(ws + 0);                 // 8 MB residual (f32)
  u16*   hb  = (u16*)(ws + ((size_t)8 << 20));   // 4 MB LN out
  u16*   qb  = (u16*)(ws + ((size_t)12 << 20));  // 4 MB (pre-scaled 0.125)
  u16*   kb  = (u16*)(ws + ((size_t)16 << 20));  // 4 MB
  u16*   vbt = (u16*)(ws + ((size_t)20 << 20));  // 4 MB V^T [D][tok]
  u16*   ab  = (u16*)(ws + ((size_t)24 << 20));  // 4 MB attn out
  u16*   mb  = (u16*)(ws + ((size_t)28 << 20));  // 16 MB gelu out
  u16*   pp  = (u16*)(ws + ((size_t)44 << 20));  // 16 MB bf16 partials
  u16*   WT  = (u16*)(ws + ((size_t)(midws ? 76 : 44) << 20));

  if (bigws)
    transw_k<<<dim3(768, 6), 256, 0, stream>>>(wq, wk, wv, wo, w1, w2, WT);
  embed_ln_k<<<NTOK, 256, 0, stream>>>(ids, wte, wpe, l1g, l1b, x, hb);

  for (int lay = 0; lay < NLAY; ++lay) {
    size_t oDD = (size_t)lay * DV * DV;
    size_t oDF = (size_t)lay * DV * FF;
    u16* WTL = bigws ? WT + (size_t)lay * 12 * 1024 * 1024 : WT;
    if (!bigws)
      transw_k<<<dim3(768, 1), 256, 0, stream>>>(wq + oDD, wk + oDD, wv + oDD,
                                                 wo + oDD, w1 + oDF, w2 + oDF, WTL);
    gemm_k<0><<<dim3(16, 8, 3), 512, 0, stream>>>(
        hb, WTL, bq + lay * DV, bk + lay * DV, bv + lay * DV,
        qb, kb, vbt, nullptr, nullptr, nullptr, NTOK, DV, DV, 0);
    attn_k<<<512, 256, 0, stream>>>(qb, kb, vbt, ab);
    if (midws) {
      gemm_k<3><<<dim3(16, 8, 4), 512, 0, stream>>>(
          ab, WTL + (size_t)3 * DV * DV, nullptr, nullptr, nullptr,
          nullptr, nullptr, nullptr, pp, nullptr, nullptr, NTOK, DV, DV, 256);
      reduce_ln_k<4, 0><<<NTOK, 256, 0, stream>>>(
          x, pp, bo + lay * DV, l2g + lay * DV, l2b + lay * DV, hb, nullptr);
    } else {
      gemm_k<2><<<dim3(16, 8, 1), 512, 0, stream>>>(
          ab, WTL + (size_t)3 * DV * DV, bo + lay * DV, nullptr, nullptr,
          nullptr, nullptr, nullptr, nullptr, x, x, NTOK, DV, DV, 0);
      ln_k<0><<<NTOK, 256, 0, stream>>>(x, l2g + lay * DV, l2b + lay * DV, hb, nullptr);
    }
    gemm_k<1><<<dim3(16, 32, 1), 512, 0, stream>>>(
        hb, WTL + (size_t)4 * DV * DV, b1 + lay * FF, nullptr, nullptr,
        mb, nullptr, nullptr, nullptr, nullptr, nullptr, NTOK, FF, DV, 0);
    if (midws) {
      gemm_k<3><<<dim3(16, 8, 4), 512, 0, stream>>>(
          mb, WTL + (size_t)8 * DV * DV, nullptr, nullptr, nullptr,
          nullptr, nullptr, nullptr, pp, nullptr, nullptr, NTOK, DV, FF, 1024);
      if (lay < NLAY - 1)
        reduce_ln_k<4, 0><<<NTOK, 256, 0, stream>>>(
            x, pp, b2 + lay * DV, l1g + (lay + 1) * DV, l1b + (lay + 1) * DV,
            hb, nullptr);
      else
        reduce_ln_k<4, 1><<<NTOK, 256, 0, stream>>>(
            x, pp, b2 + lay * DV, lfg, lfb, nullptr, (float*)d_out);
    } else {
      gemm_k<2><<<dim3(16, 8, 1), 512, 0, stream>>>(
          mb, WTL + (size_t)8 * DV * DV, b2 + lay * DV, nullptr, nullptr,
          nullptr, nullptr, nullptr, nullptr, x, x, NTOK, DV, FF, 0);
      if (lay < NLAY - 1)
        ln_k<0><<<NTOK, 256, 0, stream>>>(x, l1g + (lay + 1) * DV,
                                          l1b + (lay + 1) * DV, hb, nullptr);
      else
        ln_k<1><<<NTOK, 256, 0, stream>>>(x, lfg, lfb, nullptr, (float*)d_out);
    }
  }
}